// Round 7
// baseline (965.865 us; speedup 1.0000x reference)
//
#include <hip/hip_runtime.h>
#include <hip/hip_cooperative_groups.h>

namespace cg = cooperative_groups;

#define NN 100000
#define DD 128
#define EE 640000
#define NPAD 100352   // NN rounded up to 256 multiple
#define NCHUNK 391    // (NN+255)/256

typedef __bf16 bf16x8 __attribute__((ext_vector_type(8)));
typedef float floatx4 __attribute__((ext_vector_type(4)));

union BF8 {
    bf16x8 v;
    unsigned short u[8];
    int4 i4;
};

__device__ __forceinline__ unsigned short f2bf(float f) {
    unsigned int u = __float_as_uint(f);
    u += 0x7FFF + ((u >> 16) & 1);   // round-to-nearest-even
    return (unsigned short)(u >> 16);
}

// ---------------------------------------------------------------------------
// Cooperative kernel A: CSR build + W preconvert + aggregate, one launch.
// Phases separated by grid.sync(); all phases grid-size-agnostic stride loops.
// Replaces 8 dependent launches (2 memsets + hist/scan1/scan2/scan3/esort +
// wconv) + aggregate — round-6 accounting showed ~135 us of the 322 us wall
// time was inter-dispatch boundary overhead.
// ---------------------------------------------------------------------------
__global__ __launch_bounds__(256, 8) void build_agg_k(
    const int* __restrict__ ei, const float4* __restrict__ x4,
    const float* __restrict__ epsp,
    const float* __restrict__ W1, const float* __restrict__ W2,
    int* __restrict__ deg, int* __restrict__ offs, int* __restrict__ cursor,
    int* __restrict__ chunkSums, int* __restrict__ ssrc,
    ushort4* __restrict__ hout, unsigned short* __restrict__ wbf,
    float* __restrict__ stats) {
    cg::grid_group gg = cg::this_grid();
    const int tid = threadIdx.x;
    const int g0 = blockIdx.x * 256 + tid;
    const int gsz = gridDim.x * 256;
    __shared__ int s[512];

    // phase 0: zero deg + stats (replaces the two hipMemsetAsync)
    for (int i = g0; i < NPAD; i += gsz) deg[i] = 0;
    if (g0 < 512) stats[g0] = 0.f;
    gg.sync();

    // phase 1: degree histogram
    for (int e = g0; e < EE; e += gsz) atomicAdd(&deg[ei[EE + e]], 1);
    gg.sync();

    // phase 2: per-256-chunk exclusive scan (LDS Hillis-Steele per chunk)
    for (int c = blockIdx.x; c < NCHUNK; c += gridDim.x) {
        int g = c * 256 + tid;
        int v = (g < NN) ? deg[g] : 0;
        s[tid] = v;
        __syncthreads();
        for (int off = 1; off < 256; off <<= 1) {
            int u = (tid >= off) ? s[tid - off] : 0;
            __syncthreads();
            s[tid] += u;
            __syncthreads();
        }
        if (g < NN) offs[g] = s[tid] - v;
        if (tid == 255) chunkSums[c] = s[255];
        __syncthreads();
    }
    gg.sync();

    // phase 3: exclusive scan of 391 chunk sums, block 0, 2 elems/thread
    if (blockIdx.x == 0) {
        int v0 = (2 * tid < NCHUNK) ? chunkSums[2 * tid] : 0;
        int v1 = (2 * tid + 1 < NCHUNK) ? chunkSums[2 * tid + 1] : 0;
        int pair = v0 + v1;
        s[tid] = pair;
        __syncthreads();
        for (int off = 1; off < 256; off <<= 1) {
            int u = (tid >= off) ? s[tid - off] : 0;
            __syncthreads();
            s[tid] += u;
            __syncthreads();
        }
        int excPair = s[tid] - pair;
        if (2 * tid < NCHUNK) chunkSums[2 * tid] = excPair;
        if (2 * tid + 1 < NCHUNK) chunkSums[2 * tid + 1] = excPair + v0;
    }
    gg.sync();

    // phase 4: add chunk bases, init cursor
    for (int g = g0; g < NN; g += gsz) {
        int o = offs[g] + chunkSums[g >> 8];
        offs[g] = o;
        cursor[g] = o;
    }
    gg.sync();

    // phase 5: bucket scatter (CSR edge list sorted by dst)
    for (int e = g0; e < EE; e += gsz) {
        int pos = atomicAdd(&cursor[ei[EE + e]], 1);
        ssrc[pos] = ei[e];
    }
    gg.sync();

    // phase 6a: W fp32 -> bf16 (both layers)
    for (int i = g0; i < 8192; i += gsz) {
        const float4* s4 = (i < 4096) ? (const float4*)W1 : (const float4*)W2;
        float4 v = s4[i & 4095];
        ushort4 u;
        u.x = f2bf(v.x); u.y = f2bf(v.y); u.z = f2bf(v.z); u.w = f2bf(v.w);
        ((ushort4*)wbf)[i] = u;
    }

    // phase 6b: aggregate. 32 lanes per node; 8-wide predicated gather unroll
    // (verified round-6 body), group-stride over nodes. 8 blocks/CU resident.
    const int lane = tid & 31;
    const int grpStride = gsz >> 5;
    const float ef = 1.0f + epsp[0];
    for (int node = g0 >> 5; node < NN; node += grpStride) {
        int start = offs[node], d = deg[node];
        float4 v = x4[node * 32 + lane];
        float ax = ef * v.x, ay = ef * v.y, az = ef * v.z, aw = ef * v.w;
        for (int j = 0; j < d; j += 8) {
            int r = d - j;          // >= 1
            int b = start + j;
            int s0 = ssrc[b];
            int s1 = ssrc[b + ((r > 1) ? 1 : 0)];
            int s2 = ssrc[b + ((r > 2) ? 2 : 0)];
            int s3 = ssrc[b + ((r > 3) ? 3 : 0)];
            int s4i = ssrc[b + ((r > 4) ? 4 : 0)];
            int s5 = ssrc[b + ((r > 5) ? 5 : 0)];
            int s6 = ssrc[b + ((r > 6) ? 6 : 0)];
            int s7 = ssrc[b + ((r > 7) ? 7 : 0)];
            float4 x0 = x4[s0 * 32 + lane];
            float4 x1 = x4[s1 * 32 + lane];
            float4 x2 = x4[s2 * 32 + lane];
            float4 x3 = x4[s3 * 32 + lane];
            float4 x4v = x4[s4i * 32 + lane];
            float4 x5 = x4[s5 * 32 + lane];
            float4 x6 = x4[s6 * 32 + lane];
            float4 x7 = x4[s7 * 32 + lane];
            float m1 = (r > 1) ? 1.f : 0.f;
            float m2 = (r > 2) ? 1.f : 0.f;
            float m3 = (r > 3) ? 1.f : 0.f;
            float m4 = (r > 4) ? 1.f : 0.f;
            float m5 = (r > 5) ? 1.f : 0.f;
            float m6 = (r > 6) ? 1.f : 0.f;
            float m7 = (r > 7) ? 1.f : 0.f;
            ax += x0.x; ay += x0.y; az += x0.z; aw += x0.w;
            ax += m1 * x1.x; ay += m1 * x1.y; az += m1 * x1.z; aw += m1 * x1.w;
            ax += m2 * x2.x; ay += m2 * x2.y; az += m2 * x2.z; aw += m2 * x2.w;
            ax += m3 * x3.x; ay += m3 * x3.y; az += m3 * x3.z; aw += m3 * x3.w;
            ax += m4 * x4v.x; ay += m4 * x4v.y; az += m4 * x4v.z; aw += m4 * x4v.w;
            ax += m5 * x5.x; ay += m5 * x5.y; az += m5 * x5.z; aw += m5 * x5.w;
            ax += m6 * x6.x; ay += m6 * x6.y; az += m6 * x6.z; aw += m6 * x6.w;
            ax += m7 * x7.x; ay += m7 * x7.y; az += m7 * x7.z; aw += m7 * x7.w;
        }
        ushort4 u;
        u.x = f2bf(ax); u.y = f2bf(ay); u.z = f2bf(az); u.w = f2bf(aw);
        hout[node * 32 + lane] = u;
    }
}

// ---------------------------------------------------------------------------
// Persistent-W GEMM body (verified round-6 code as a device function).
// Whole bf16 W in registers; grid-stride over 16-row tiles, prefetch depth 1;
// epilogue staged through wave-private LDS for fully-covered 128B-line stores.
// FUSE_BN=1: BN(statsIn)+ReLU applied to fp32 yin in the loader (in-place ok:
// tile ownership by residue class).
// ---------------------------------------------------------------------------
template <int FUSE_BN>
__device__ __forceinline__ void gemm_body(
    const unsigned short* __restrict__ hin, const float* __restrict__ yin,
    const float* __restrict__ statsIn, const float* __restrict__ gmm,
    const float* __restrict__ bta, const unsigned short* __restrict__ Wbf,
    const float* __restrict__ bias, float* __restrict__ y,
    float* __restrict__ statsOut, float* __restrict__ s_sum,
    float* __restrict__ s_sq, float* __restrict__ sc, float* __restrict__ sh,
    float* __restrict__ yst) {
    const int tid = threadIdx.x;
    const int l = tid & 63, w = tid >> 6;
    const int m = l & 15, q = l >> 4;

    if (tid < 128) {
        s_sum[tid] = 0.f;
        s_sq[tid] = 0.f;
        if (FUSE_BN) {
            const float inv = 1.0f / (float)NN;
            float mean = statsIn[tid] * inv;
            float var = statsIn[128 + tid] * inv - mean * mean;
            float sv = gmm[tid] * rsqrtf(var + 1e-5f);
            sc[tid] = sv;
            sh[tid] = bta[tid] - mean * sv;
        }
    }

    // whole W into registers, once per wave per layer
    bf16x8 wf[8][4];
#pragma unroll
    for (int ct = 0; ct < 8; ++ct) {
        const unsigned short* wr = Wbf + (size_t)(ct * 16 + m) * 128 + q * 8;
#pragma unroll
        for (int kc = 0; kc < 4; ++kc) {
            BF8 t;
            t.i4 = *(const int4*)(wr + kc * 32);
            wf[ct][kc] = t.v;
        }
    }
    float bc[8];
#pragma unroll
    for (int ct = 0; ct < 8; ++ct) bc[ct] = bias[ct * 16 + m];

    float ps[8], pq[8];
#pragma unroll
    for (int ct = 0; ct < 8; ++ct) { ps[ct] = 0.f; pq[ct] = 0.f; }

    __syncthreads();  // s_sum/s_sq (and sc/sh) visible

    const int NT = NN / 16;                 // 6250, exact
    const int stride = gridDim.x * 4;       // waves total
    int t = blockIdx.x * 4 + w;

    const unsigned short* abase = hin + (size_t)m * 128 + q * 8;
    const float* ybase = yin + (size_t)m * 128 + q * 8;

    int4 ra[4];      // FUSE_BN=0 prefetch
    float4 rf[8];    // FUSE_BN=1 prefetch
    if (t < NT) {
        if (FUSE_BN) {
            const float* yp = ybase + (size_t)t * (16 * 128);
#pragma unroll
            for (int i = 0; i < 8; ++i)
                rf[i] = *(const float4*)(yp + (i >> 1) * 32 + (i & 1) * 4);
        } else {
            const unsigned short* ap = abase + (size_t)t * (16 * 128);
#pragma unroll
            for (int kc = 0; kc < 4; ++kc) ra[kc] = *(const int4*)(ap + kc * 32);
        }
    }

    float* ytile = yst + w * (16 * 132);

    while (t < NT) {
        bf16x8 a[4];
#pragma unroll
        for (int kc = 0; kc < 4; ++kc) {
            if (FUSE_BN) {
                float4 v0 = rf[2 * kc], v1 = rf[2 * kc + 1];
                float4 s0 = *(const float4*)(sc + kc * 32 + q * 8);
                float4 s1 = *(const float4*)(sc + kc * 32 + q * 8 + 4);
                float4 h0 = *(const float4*)(sh + kc * 32 + q * 8);
                float4 h1 = *(const float4*)(sh + kc * 32 + q * 8 + 4);
                BF8 tt;
                tt.u[0] = f2bf(fmaxf(v0.x * s0.x + h0.x, 0.f));
                tt.u[1] = f2bf(fmaxf(v0.y * s0.y + h0.y, 0.f));
                tt.u[2] = f2bf(fmaxf(v0.z * s0.z + h0.z, 0.f));
                tt.u[3] = f2bf(fmaxf(v0.w * s0.w + h0.w, 0.f));
                tt.u[4] = f2bf(fmaxf(v1.x * s1.x + h1.x, 0.f));
                tt.u[5] = f2bf(fmaxf(v1.y * s1.y + h1.y, 0.f));
                tt.u[6] = f2bf(fmaxf(v1.z * s1.z + h1.z, 0.f));
                tt.u[7] = f2bf(fmaxf(v1.w * s1.w + h1.w, 0.f));
                a[kc] = tt.v;
            } else {
                BF8 tt;
                tt.i4 = ra[kc];
                a[kc] = tt.v;
            }
        }

        int tn = t + stride;
        if (tn < NT) {
            if (FUSE_BN) {
                const float* yp = ybase + (size_t)tn * (16 * 128);
#pragma unroll
                for (int i = 0; i < 8; ++i)
                    rf[i] = *(const float4*)(yp + (i >> 1) * 32 + (i & 1) * 4);
            } else {
                const unsigned short* ap = abase + (size_t)tn * (16 * 128);
#pragma unroll
                for (int kc = 0; kc < 4; ++kc) ra[kc] = *(const int4*)(ap + kc * 32);
            }
        }

        floatx4 acc[8];
#pragma unroll
        for (int ct = 0; ct < 8; ++ct) acc[ct] = (floatx4)0.0f;
#pragma unroll
        for (int kc = 0; kc < 4; ++kc)
#pragma unroll
            for (int ct = 0; ct < 8; ++ct)
                acc[ct] = __builtin_amdgcn_mfma_f32_16x16x32_bf16(a[kc], wf[ct][kc], acc[ct], 0, 0, 0);

        // epilogue: bias + stats, stage tile in wave-private LDS, then store
        // full float4 rows (lanes 0-31 = 512B contiguous, full 128B lines)
#pragma unroll
        for (int ct = 0; ct < 8; ++ct) {
#pragma unroll
            for (int i = 0; i < 4; ++i) {
                float yv = acc[ct][i] + bc[ct];
                ytile[(q * 4 + i) * 132 + ct * 16 + m] = yv;
                ps[ct] += yv;
                pq[ct] += yv * yv;
            }
        }
        asm volatile("s_waitcnt lgkmcnt(0)" ::: "memory");
        float* yb = y + (size_t)t * (16 * 128);
#pragma unroll
        for (int it = 0; it < 8; ++it) {
            int f4 = it * 64 + l;
            int row = f4 >> 5, c4 = f4 & 31;
            float4 vv = *(const float4*)&ytile[row * 132 + c4 * 4];
            *(float4*)(yb + row * 128 + c4 * 4) = vv;
        }
        t = tn;
    }

    // flush register stats: LDS reduce, then 2 global atomics per column
#pragma unroll
    for (int ct = 0; ct < 8; ++ct) {
        atomicAdd(&s_sum[ct * 16 + m], ps[ct]);
        atomicAdd(&s_sq[ct * 16 + m], pq[ct]);
    }
    __syncthreads();
    if (tid < 128) {
        unsafeAtomicAdd(&statsOut[tid], s_sum[tid]);
        unsafeAtomicAdd(&statsOut[128 + tid], s_sq[tid]);
    }
}

// ---------------------------------------------------------------------------
// Cooperative kernel B: gemm1 -> sync -> gemm2 (BN1-fused, in place) -> sync
// -> BN2+ReLU in place. One launch instead of three.
// ---------------------------------------------------------------------------
__global__ __launch_bounds__(256, 2) void mlp_k(
    const unsigned short* __restrict__ hbuf,
    const unsigned short* __restrict__ wbf,
    const float* __restrict__ b1, const float* __restrict__ g1,
    const float* __restrict__ be1, const float* __restrict__ b2,
    const float* __restrict__ g2, const float* __restrict__ be2,
    float* __restrict__ out, float* __restrict__ stats) {
    cg::grid_group gg = cg::this_grid();
    __shared__ __align__(16) float s_sum[128];
    __shared__ __align__(16) float s_sq[128];
    __shared__ __align__(16) float sc[128];
    __shared__ __align__(16) float sh[128];
    __shared__ __align__(16) float yst[4 * 16 * 132];

    gemm_body<0>(hbuf, nullptr, nullptr, nullptr, nullptr, wbf, b1, out, stats,
                 s_sum, s_sq, sc, sh, yst);
    gg.sync();  // stats1 + y1 complete device-wide
    gemm_body<1>(nullptr, out, stats, g1, be1, wbf + 16384, b2, out,
                 stats + 256, s_sum, s_sq, sc, sh, yst);
    gg.sync();  // stats2 complete

    // BN2 + ReLU in place
    const int tid = threadIdx.x;
    if (tid < 128) {
        const float inv = 1.0f / (float)NN;
        float mean = stats[256 + tid] * inv;
        float var = stats[384 + tid] * inv - mean * mean;
        float sv = g2[tid] * rsqrtf(var + 1e-5f);
        sc[tid] = sv;
        sh[tid] = be2[tid] - mean * sv;
    }
    __syncthreads();
    const int total4 = NN * 32;
    float4* y4 = (float4*)out;
    for (int i = blockIdx.x * 256 + tid; i < total4; i += gridDim.x * 256) {
        int c4 = i & 31;
        float4 v = y4[i];
        float4 sv = ((const float4*)sc)[c4];
        float4 bv = ((const float4*)sh)[c4];
        y4[i] = make_float4(fmaxf(v.x * sv.x + bv.x, 0.f),
                            fmaxf(v.y * sv.y + bv.y, 0.f),
                            fmaxf(v.z * sv.z + bv.z, 0.f),
                            fmaxf(v.w * sv.w + bv.w, 0.f));
    }
}

// ---------------------------------------------------------------------------
extern "C" void kernel_launch(void* const* d_in, const int* in_sizes, int n_in,
                              void* d_out, int out_size, void* d_ws, size_t ws_size,
                              hipStream_t stream) {
    const int* ei    = (const int*)d_in[1];   // int64 in ref -> int32 from harness
    const float* eps = (const float*)d_in[2];
    const float* W1  = (const float*)d_in[3];
    const float* b1  = (const float*)d_in[4];
    const float* g1  = (const float*)d_in[5];
    const float* be1 = (const float*)d_in[6];
    const float* W2  = (const float*)d_in[7];
    const float* b2  = (const float*)d_in[8];
    const float* g2  = (const float*)d_in[9];
    const float* be2 = (const float*)d_in[10];
    const float4* x4 = (const float4*)d_in[0];
    float* out = (float*)d_out;

    // Workspace (~29.6 MB): [csr][hbuf bf16 25.6MB][stats 2KB][wbf 64KB]
    int* deg        = (int*)d_ws;           // NPAD
    int* offs       = deg + NPAD;           // NPAD
    int* cursor     = offs + NPAD;          // NPAD
    int* chunkSums  = cursor + NPAD;        // 512
    int* ssrc       = chunkSums + 512;      // EE + pad
    unsigned short* hbuf = (unsigned short*)(ssrc + EE + 256);   // N*D bf16
    float* stats    = (float*)(hbuf + (size_t)NN * DD);          // 512
    unsigned short* wbf = (unsigned short*)(stats + 512);        // 2*128*128 bf16
    ushort4* hout   = (ushort4*)hbuf;

    // Co-residency-safe grids for cooperative launch (all phases grid-size-
    // agnostic stride loops, so any block count is correct).
    int nbA = 0, nbB = 0;
    if (hipOccupancyMaxActiveBlocksPerMultiprocessor(&nbA, build_agg_k, 256, 0) != hipSuccess || nbA < 1) nbA = 4;
    if (hipOccupancyMaxActiveBlocksPerMultiprocessor(&nbB, mlp_k, 256, 0) != hipSuccess || nbB < 1) nbB = 2;
    if (nbA > 8) nbA = 8;
    if (nbB > 8) nbB = 8;
    dim3 blk(256);
    dim3 gridA(nbA * 256);
    dim3 gridB(nbB * 256);

    void* argsA[] = {(void*)&ei, (void*)&x4, (void*)&eps, (void*)&W1, (void*)&W2,
                     (void*)&deg, (void*)&offs, (void*)&cursor, (void*)&chunkSums,
                     (void*)&ssrc, (void*)&hout, (void*)&wbf, (void*)&stats};
    hipLaunchCooperativeKernel(build_agg_k, gridA, blk, argsA, 0, stream);

    void* argsB[] = {(void*)&hbuf, (void*)&wbf, (void*)&b1, (void*)&g1,
                     (void*)&be1, (void*)&b2, (void*)&g2, (void*)&be2,
                     (void*)&out, (void*)&stats};
    hipLaunchCooperativeKernel(mlp_k, gridB, blk, argsB, 0, stream);
}

// Round 8
// 409.673 us; speedup vs baseline: 2.3576x; 2.3576x over previous
//
#include <hip/hip_runtime.h>

#define NN 100000
#define DD 128
#define EE 640000
#define NPAD 100352   // NN rounded up to 256 multiple
#define NCHUNK 391    // (NN+255)/256

typedef __bf16 bf16x8 __attribute__((ext_vector_type(8)));
typedef float floatx4 __attribute__((ext_vector_type(4)));

union BF8 {
    bf16x8 v;
    unsigned short u[8];
    int4 i4;
};

__device__ __forceinline__ unsigned short f2bf(float f) {
    unsigned int u = __float_as_uint(f);
    u += 0x7FFF + ((u >> 16) & 1);   // round-to-nearest-even
    return (unsigned short)(u >> 16);
}

// ---------------------------------------------------------------------------
// CSR build, compacted to 3 dispatches (was 5 + 2 memsets):
//   hist -> scanlb (single-kernel decoupled-lookback scan) -> esort(+wconv)
// ---------------------------------------------------------------------------
__global__ __launch_bounds__(256) void hist_k(const int* __restrict__ ei,
                                              int* __restrict__ deg) {
    int e = blockIdx.x * 256 + threadIdx.x;
    if (e < EE) atomicAdd(&deg[ei[EE + e]], 1);
}

// Single-pass exclusive scan over NN degrees, 391 blocks (all co-resident on
// 256 CUs -> lookback cannot deadlock). descr[c]: bits31..30 flag (0=empty,
// 1=aggregate, 2=inclusive-prefix), bits29..0 sum (max EE=640000 < 2^30).
__global__ __launch_bounds__(256) void scanlb_k(
    const int* __restrict__ deg, unsigned int* __restrict__ descr,
    int* __restrict__ offs, int* __restrict__ cursor) {
    __shared__ int s[256];
    __shared__ int sbase;
    const int c = blockIdx.x, t = threadIdx.x;
    int g = c * 256 + t;
    int v = (g < NN) ? deg[g] : 0;
    s[t] = v;
    __syncthreads();
    for (int off = 1; off < 256; off <<= 1) {
        int u = (t >= off) ? s[t - off] : 0;
        __syncthreads();
        s[t] += u;
        __syncthreads();
    }
    const int total = s[255];
    if (t == 0) {
        if (c == 0) {
            __hip_atomic_store(&descr[0], (2u << 30) | (unsigned)total,
                               __ATOMIC_RELEASE, __HIP_MEMORY_SCOPE_AGENT);
            sbase = 0;
        } else {
            __hip_atomic_store(&descr[c], (1u << 30) | (unsigned)total,
                               __ATOMIC_RELEASE, __HIP_MEMORY_SCOPE_AGENT);
            int acc = 0, p = c - 1;
            while (true) {
                unsigned st = __hip_atomic_load(&descr[p], __ATOMIC_ACQUIRE,
                                                __HIP_MEMORY_SCOPE_AGENT);
                unsigned fl = st >> 30;
                if (fl == 0u) continue;   // predecessor not published yet
                acc += (int)(st & 0x3FFFFFFFu);
                if (fl == 2u) break;
                --p;
            }
            __hip_atomic_store(&descr[c], (2u << 30) | (unsigned)(acc + total),
                               __ATOMIC_RELEASE, __HIP_MEMORY_SCOPE_AGENT);
            sbase = acc;
        }
    }
    __syncthreads();
    if (g < NN) {
        int o = sbase + s[t] - v;   // exclusive prefix
        offs[g] = o;
        cursor[g] = o;
    }
}

// esort (blocks 0..2499; EE = 2500*256 exactly) + folded-in W fp32->bf16
// preconvert and stats zeroing (blocks 2500..2531).
__global__ __launch_bounds__(256) void esort_k(
    const int* __restrict__ ei, int* __restrict__ cursor,
    int* __restrict__ ssrc, const float* __restrict__ W1,
    const float* __restrict__ W2, unsigned short* __restrict__ wbf,
    float* __restrict__ stats) {
    int b = blockIdx.x;
    if (b >= 2500) {
        int i = (b - 2500) * 256 + threadIdx.x;   // 0..8191 float4 units
        if (b == 2500) {
            stats[threadIdx.x] = 0.f;
            stats[256 + threadIdx.x] = 0.f;
        }
        const float4* s4 = (i < 4096) ? (const float4*)W1 : (const float4*)W2;
        float4 v = s4[i & 4095];
        ushort4 u;
        u.x = f2bf(v.x); u.y = f2bf(v.y); u.z = f2bf(v.z); u.w = f2bf(v.w);
        ((ushort4*)wbf)[i] = u;
        return;
    }
    int e = b * 256 + threadIdx.x;
    int pos = atomicAdd(&cursor[ei[EE + e]], 1);
    ssrc[pos] = ei[e];
}

// ---------------------------------------------------------------------------
// aggregate + fuse: h[node] = bf16((1+eps)*x[node] + sum_{src in CSR} x[src])
// 32 lanes (float4) per node; launch_bounds(256,4) + 8-wide predicated
// unroll -> 8 row gathers in flight. (Round-7 lesson: capping this grid to a
// cooperative-resident size serialized the gather chains -> 220 GB/s. Keep
// 12500 independent blocks.)
// ---------------------------------------------------------------------------
__global__ __launch_bounds__(256, 4) void aggregate_k(
    const float4* __restrict__ x4, const int* __restrict__ ssrc,
    const int* __restrict__ offs, const int* __restrict__ deg,
    const float* __restrict__ epsp, ushort4* __restrict__ hout) {
    int tid = blockIdx.x * 256 + threadIdx.x;
    int node = tid >> 5, lane = tid & 31;
    if (node >= NN) return;
    int start = offs[node], d = deg[node];
    float ef = 1.0f + epsp[0];
    float4 v = x4[node * 32 + lane];
    float ax = ef * v.x, ay = ef * v.y, az = ef * v.z, aw = ef * v.w;
    for (int j = 0; j < d; j += 8) {
        int r = d - j;          // >= 1
        int b = start + j;
        int s0 = ssrc[b];
        int s1 = ssrc[b + ((r > 1) ? 1 : 0)];
        int s2 = ssrc[b + ((r > 2) ? 2 : 0)];
        int s3 = ssrc[b + ((r > 3) ? 3 : 0)];
        int s4i = ssrc[b + ((r > 4) ? 4 : 0)];
        int s5 = ssrc[b + ((r > 5) ? 5 : 0)];
        int s6 = ssrc[b + ((r > 6) ? 6 : 0)];
        int s7 = ssrc[b + ((r > 7) ? 7 : 0)];
        float4 x0 = x4[s0 * 32 + lane];
        float4 x1 = x4[s1 * 32 + lane];
        float4 x2 = x4[s2 * 32 + lane];
        float4 x3 = x4[s3 * 32 + lane];
        float4 x4v = x4[s4i * 32 + lane];
        float4 x5 = x4[s5 * 32 + lane];
        float4 x6 = x4[s6 * 32 + lane];
        float4 x7 = x4[s7 * 32 + lane];
        float m1 = (r > 1) ? 1.f : 0.f;
        float m2 = (r > 2) ? 1.f : 0.f;
        float m3 = (r > 3) ? 1.f : 0.f;
        float m4 = (r > 4) ? 1.f : 0.f;
        float m5 = (r > 5) ? 1.f : 0.f;
        float m6 = (r > 6) ? 1.f : 0.f;
        float m7 = (r > 7) ? 1.f : 0.f;
        ax += x0.x; ay += x0.y; az += x0.z; aw += x0.w;
        ax += m1 * x1.x; ay += m1 * x1.y; az += m1 * x1.z; aw += m1 * x1.w;
        ax += m2 * x2.x; ay += m2 * x2.y; az += m2 * x2.z; aw += m2 * x2.w;
        ax += m3 * x3.x; ay += m3 * x3.y; az += m3 * x3.z; aw += m3 * x3.w;
        ax += m4 * x4v.x; ay += m4 * x4v.y; az += m4 * x4v.z; aw += m4 * x4v.w;
        ax += m5 * x5.x; ay += m5 * x5.y; az += m5 * x5.z; aw += m5 * x5.w;
        ax += m6 * x6.x; ay += m6 * x6.y; az += m6 * x6.z; aw += m6 * x6.w;
        ax += m7 * x7.x; ay += m7 * x7.y; az += m7 * x7.z; aw += m7 * x7.w;
    }
    ushort4 u;
    u.x = f2bf(ax); u.y = f2bf(ay); u.z = f2bf(az); u.w = f2bf(aw);
    hout[node * 32 + lane] = u;
}

// ---------------------------------------------------------------------------
// Persistent-W GEMM + bias + BN-stat accumulation (round-6 verified body).
// Whole bf16 W in registers (32 x bf16x8); grid-stride over 16-row tiles,
// prefetch depth 1; epilogue staged through wave-private LDS for fully-
// covered 128B-line stores. FUSE_BN=1: BN(statsIn)+ReLU applied to fp32 yin
// in the loader (in-place y1->y2 safe: tile ownership by residue class).
// ---------------------------------------------------------------------------
template <int FUSE_BN>
__global__ __launch_bounds__(256, 2) void gin_gemm_k(
    const unsigned short* __restrict__ hin,
    const float* __restrict__ yin,
    const float* __restrict__ statsIn,
    const float* __restrict__ gmm,
    const float* __restrict__ bta,
    const unsigned short* __restrict__ Wbf, const float* __restrict__ bias,
    float* __restrict__ y, float* __restrict__ statsOut) {
    __shared__ __align__(16) float s_sum[128];
    __shared__ __align__(16) float s_sq[128];
    __shared__ __align__(16) float sc[128];
    __shared__ __align__(16) float sh[128];
    __shared__ __align__(16) float yst[4][16][132];  // per-wave tile, +4 pad

    const int tid = threadIdx.x;
    const int l = tid & 63, w = tid >> 6;
    const int m = l & 15, q = l >> 4;

    if (tid < 128) {
        s_sum[tid] = 0.f;
        s_sq[tid] = 0.f;
        if (FUSE_BN) {
            const float inv = 1.0f / (float)NN;
            float mean = statsIn[tid] * inv;
            float var = statsIn[128 + tid] * inv - mean * mean;
            float s = gmm[tid] * rsqrtf(var + 1e-5f);
            sc[tid] = s;
            sh[tid] = bta[tid] - mean * s;
        }
    }

    // --- whole W into registers, once per wave ---
    bf16x8 wf[8][4];
#pragma unroll
    for (int ct = 0; ct < 8; ++ct) {
        const unsigned short* wr = Wbf + (size_t)(ct * 16 + m) * 128 + q * 8;
#pragma unroll
        for (int kc = 0; kc < 4; ++kc) {
            BF8 t;
            t.i4 = *(const int4*)(wr + kc * 32);
            wf[ct][kc] = t.v;
        }
    }
    float bc[8];
#pragma unroll
    for (int ct = 0; ct < 8; ++ct) bc[ct] = bias[ct * 16 + m];

    float ps[8], pq[8];
#pragma unroll
    for (int ct = 0; ct < 8; ++ct) { ps[ct] = 0.f; pq[ct] = 0.f; }

    __syncthreads();  // s_sum/s_sq (and sc/sh) visible

    const int NT = NN / 16;              // 6250, exact
    const int stride = gridDim.x * 4;    // waves total
    int t = blockIdx.x * 4 + w;

    const unsigned short* abase = hin + (size_t)m * 128 + q * 8;
    const float* ybase = yin + (size_t)m * 128 + q * 8;

    int4 ra[4];      // FUSE_BN=0 prefetch
    float4 rf[8];    // FUSE_BN=1 prefetch
    if (t < NT) {
        if (FUSE_BN) {
            const float* yp = ybase + (size_t)t * (16 * 128);
#pragma unroll
            for (int i = 0; i < 8; ++i)
                rf[i] = *(const float4*)(yp + (i >> 1) * 32 + (i & 1) * 4);
        } else {
            const unsigned short* ap = abase + (size_t)t * (16 * 128);
#pragma unroll
            for (int kc = 0; kc < 4; ++kc) ra[kc] = *(const int4*)(ap + kc * 32);
        }
    }

    while (t < NT) {
        bf16x8 a[4];
#pragma unroll
        for (int kc = 0; kc < 4; ++kc) {
            if (FUSE_BN) {
                float4 v0 = rf[2 * kc], v1 = rf[2 * kc + 1];
                float4 s0 = *(const float4*)(sc + kc * 32 + q * 8);
                float4 s1 = *(const float4*)(sc + kc * 32 + q * 8 + 4);
                float4 h0 = *(const float4*)(sh + kc * 32 + q * 8);
                float4 h1 = *(const float4*)(sh + kc * 32 + q * 8 + 4);
                BF8 tt;
                tt.u[0] = f2bf(fmaxf(v0.x * s0.x + h0.x, 0.f));
                tt.u[1] = f2bf(fmaxf(v0.y * s0.y + h0.y, 0.f));
                tt.u[2] = f2bf(fmaxf(v0.z * s0.z + h0.z, 0.f));
                tt.u[3] = f2bf(fmaxf(v0.w * s0.w + h0.w, 0.f));
                tt.u[4] = f2bf(fmaxf(v1.x * s1.x + h1.x, 0.f));
                tt.u[5] = f2bf(fmaxf(v1.y * s1.y + h1.y, 0.f));
                tt.u[6] = f2bf(fmaxf(v1.z * s1.z + h1.z, 0.f));
                tt.u[7] = f2bf(fmaxf(v1.w * s1.w + h1.w, 0.f));
                a[kc] = tt.v;
            } else {
                BF8 tt;
                tt.i4 = ra[kc];
                a[kc] = tt.v;
            }
        }

        int tn = t + stride;
        if (tn < NT) {
            if (FUSE_BN) {
                const float* yp = ybase + (size_t)tn * (16 * 128);
#pragma unroll
                for (int i = 0; i < 8; ++i)
                    rf[i] = *(const float4*)(yp + (i >> 1) * 32 + (i & 1) * 4);
            } else {
                const unsigned short* ap = abase + (size_t)tn * (16 * 128);
#pragma unroll
                for (int kc = 0; kc < 4; ++kc) ra[kc] = *(const int4*)(ap + kc * 32);
            }
        }

        floatx4 acc[8];
#pragma unroll
        for (int ct = 0; ct < 8; ++ct) acc[ct] = (floatx4)0.0f;
#pragma unroll
        for (int kc = 0; kc < 4; ++kc)
#pragma unroll
            for (int ct = 0; ct < 8; ++ct)
                acc[ct] = __builtin_amdgcn_mfma_f32_16x16x32_bf16(a[kc], wf[ct][kc], acc[ct], 0, 0, 0);

        // epilogue: bias + stats, stage tile in wave-private LDS, then store
        // full float4 rows (lanes 0-31 = 512B contiguous, full 128B lines)
#pragma unroll
        for (int ct = 0; ct < 8; ++ct) {
#pragma unroll
            for (int i = 0; i < 4; ++i) {
                float yv = acc[ct][i] + bc[ct];
                yst[w][q * 4 + i][ct * 16 + m] = yv;
                ps[ct] += yv;
                pq[ct] += yv * yv;
            }
        }
        asm volatile("s_waitcnt lgkmcnt(0)" ::: "memory");
        float* yb = y + (size_t)t * (16 * 128);
#pragma unroll
        for (int it = 0; it < 8; ++it) {
            int f4 = it * 64 + l;
            int row = f4 >> 5, c4 = f4 & 31;
            float4 vv = *(const float4*)&yst[w][row][c4 * 4];
            *(float4*)(yb + row * 128 + c4 * 4) = vv;
        }
        t = tn;
    }

    // flush register stats: LDS reduce, then 2 global atomics per column
#pragma unroll
    for (int ct = 0; ct < 8; ++ct) {
        atomicAdd(&s_sum[ct * 16 + m], ps[ct]);
        atomicAdd(&s_sq[ct * 16 + m], pq[ct]);
    }
    __syncthreads();
    if (tid < 128) {
        unsafeAtomicAdd(&statsOut[tid], s_sum[tid]);
        unsafeAtomicAdd(&statsOut[128 + tid], s_sq[tid]);
    }
}

// ---------------------------------------------------------------------------
// BN(train, biased var) + ReLU, fp32 in place (final layer only).
// ---------------------------------------------------------------------------
__global__ __launch_bounds__(256) void bn_relu_k(
    const float* __restrict__ y, const float* __restrict__ stats,
    const float* __restrict__ g, const float* __restrict__ beta,
    float* __restrict__ outf) {
    __shared__ __align__(16) float sc[128];
    __shared__ __align__(16) float sh[128];
    int t = threadIdx.x;
    if (t < 128) {
        const float inv = 1.0f / (float)NN;
        float mean = stats[t] * inv;
        float var = stats[128 + t] * inv - mean * mean;
        float s = g[t] * rsqrtf(var + 1e-5f);
        sc[t] = s;
        sh[t] = beta[t] - mean * s;
    }
    __syncthreads();
    const int total4 = NN * 32;
    const float4* y4 = (const float4*)y;
    for (int i = blockIdx.x * 256 + t; i < total4; i += gridDim.x * 256) {
        int c4 = i & 31;
        float4 v = y4[i];
        float4 s = ((const float4*)sc)[c4];
        float4 b = ((const float4*)sh)[c4];
        float r0 = fmaxf(v.x * s.x + b.x, 0.f);
        float r1 = fmaxf(v.y * s.y + b.y, 0.f);
        float r2 = fmaxf(v.z * s.z + b.z, 0.f);
        float r3 = fmaxf(v.w * s.w + b.w, 0.f);
        ((float4*)outf)[i] = make_float4(r0, r1, r2, r3);
    }
}

// ---------------------------------------------------------------------------
extern "C" void kernel_launch(void* const* d_in, const int* in_sizes, int n_in,
                              void* d_out, int out_size, void* d_ws, size_t ws_size,
                              hipStream_t stream) {
    const float* x   = (const float*)d_in[0];
    const int* ei    = (const int*)d_in[1];   // int64 in ref -> int32 from harness
    const float* eps = (const float*)d_in[2];
    const float* W1  = (const float*)d_in[3];
    const float* b1  = (const float*)d_in[4];
    const float* g1  = (const float*)d_in[5];
    const float* be1 = (const float*)d_in[6];
    const float* W2  = (const float*)d_in[7];
    const float* b2  = (const float*)d_in[8];
    const float* g2  = (const float*)d_in[9];
    const float* be2 = (const float*)d_in[10];
    float* out = (float*)d_out;

    // Workspace (~29.6 MB):
    // [deg NPAD][descr 512][offs NPAD][cursor NPAD][ssrc EE+256]
    // [hbuf bf16 25.6MB][stats 512f][wbf 2*128*128 bf16]
    int* deg            = (int*)d_ws;
    unsigned int* descr = (unsigned int*)(deg + NPAD);      // 512 (>= NCHUNK)
    int* offs           = (int*)(descr + 512);
    int* cursor         = offs + NPAD;
    int* ssrc           = cursor + NPAD;
    unsigned short* hbuf = (unsigned short*)(ssrc + EE + 256);
    float* stats        = (float*)(hbuf + (size_t)NN * DD);
    unsigned short* wbf = (unsigned short*)(stats + 512);

    // one memset covers deg + lookback descriptors (adjacent)
    hipMemsetAsync(deg, 0, (NPAD + 512) * sizeof(int), stream);

    hist_k<<<(EE + 255) / 256, 256, 0, stream>>>(ei, deg);
    scanlb_k<<<NCHUNK, 256, 0, stream>>>(deg, descr, offs, cursor);
    esort_k<<<2500 + 32, 256, 0, stream>>>(ei, cursor, ssrc, W1, W2, wbf, stats);
    aggregate_k<<<(NN * 32 + 255) / 256, 256, 0, stream>>>(
        (const float4*)x, ssrc, offs, deg, eps, (ushort4*)hbuf);

    const int gblocks = 512;  // ~2 blocks/CU, persistent grid-stride
    gin_gemm_k<0><<<gblocks, 256, 0, stream>>>(
        hbuf, nullptr, nullptr, nullptr, nullptr, wbf, b1, out, stats);
    gin_gemm_k<1><<<gblocks, 256, 0, stream>>>(
        nullptr, out, stats, g1, be1, wbf + 16384, b2, out, stats + 256);
    bn_relu_k<<<4096, 256, 0, stream>>>(out, stats + 256, g2, be2, out);
}

// Round 9
// 330.303 us; speedup vs baseline: 2.9242x; 1.2403x over previous
//
#include <hip/hip_runtime.h>

#define NN 100000
#define DD 128
#define EE 640000
#define NPAD 100352   // NN rounded up to 256 multiple
#define NCHUNK 391    // (NN+255)/256

typedef __bf16 bf16x8 __attribute__((ext_vector_type(8)));
typedef float floatx4 __attribute__((ext_vector_type(4)));

union BF8 {
    bf16x8 v;
    unsigned short u[8];
    int4 i4;
};

__device__ __forceinline__ unsigned short f2bf(float f) {
    unsigned int u = __float_as_uint(f);
    u += 0x7FFF + ((u >> 16) & 1);   // round-to-nearest-even
    return (unsigned short)(u >> 16);
}

// ---------------------------------------------------------------------------
// CSR build: hist -> scanlb (single-kernel decoupled-lookback scan, wave-
// parallel lookback window) -> esort(+wconv+stats-zero)
// ---------------------------------------------------------------------------
__global__ __launch_bounds__(256) void hist_k(const int* __restrict__ ei,
                                              int* __restrict__ deg) {
    int e = blockIdx.x * 256 + threadIdx.x;
    if (e < EE) atomicAdd(&deg[ei[EE + e]], 1);
}

// Single-pass exclusive scan over NN degrees. descr[c]: bits31..30 flag
// (0=empty, 1=aggregate, 2=inclusive-prefix), bits29..0 sum (EE < 2^30).
// Round-8 lesson: single-thread lookback = c serial ~270ns agent-acquire
// loads -> 106us for block 390. Now wave 0's 64 lanes read 64 descriptors
// per round (<=7 rounds worst case).
__global__ __launch_bounds__(256) void scanlb_k(
    const int* __restrict__ deg, unsigned int* __restrict__ descr,
    int* __restrict__ offs, int* __restrict__ cursor) {
    __shared__ int s[256];
    __shared__ int sbase;
    const int c = blockIdx.x, t = threadIdx.x;
    int g = c * 256 + t;
    int v = (g < NN) ? deg[g] : 0;
    s[t] = v;
    __syncthreads();
    for (int off = 1; off < 256; off <<= 1) {
        int u = (t >= off) ? s[t - off] : 0;
        __syncthreads();
        s[t] += u;
        __syncthreads();
    }
    const int total = s[255];
    if (c == 0) {
        if (t == 0) {
            __hip_atomic_store(&descr[0], (2u << 30) | (unsigned)total,
                               __ATOMIC_RELEASE, __HIP_MEMORY_SCOPE_AGENT);
            sbase = 0;
        }
    } else if (t < 64) {
        // publish our aggregate first (flag 1) so successors can progress
        if (t == 0)
            __hip_atomic_store(&descr[c], (1u << 30) | (unsigned)total,
                               __ATOMIC_RELEASE, __HIP_MEMORY_SCOPE_AGENT);
        int acc = 0;
        int base = c - 1;              // lane l inspects block (base - l)
        while (true) {
            int p = base - t;
            unsigned st = (p >= 0)
                ? __hip_atomic_load(&descr[p], __ATOMIC_ACQUIRE,
                                    __HIP_MEMORY_SCOPE_AGENT)
                : (2u << 30);          // virtual block -1: prefix 0
            unsigned fl = st >> 30;
            unsigned long long b2 = __ballot(fl == 2u);
            unsigned long long b0 = __ballot(fl == 0u);
            int l2 = b2 ? (__ffsll(b2) - 1) : 64;   // nearest inclusive-prefix
            int l0 = b0 ? (__ffsll(b0) - 1) : 64;   // nearest unpublished
            if (l0 < l2) continue;     // blocked by an empty slot: retry window
            unsigned contrib = (t <= l2) ? (st & 0x3FFFFFFFu) : 0u;
#pragma unroll
            for (int o2 = 32; o2 > 0; o2 >>= 1)
                contrib += __shfl_down(contrib, o2, 64);
            contrib = __shfl(contrib, 0, 64);
            acc += (int)contrib;
            if (l2 < 64) break;        // absorbed an inclusive prefix: done
            base -= 64;                // window was all aggregates: step back
        }
        if (t == 0) {
            sbase = acc;
            __hip_atomic_store(&descr[c], (2u << 30) | (unsigned)(acc + total),
                               __ATOMIC_RELEASE, __HIP_MEMORY_SCOPE_AGENT);
        }
    }
    __syncthreads();
    if (g < NN) {
        int o = sbase + s[t] - v;   // exclusive prefix
        offs[g] = o;
        cursor[g] = o;
    }
}

// esort (blocks 0..2499; EE = 2500*256 exactly) + folded-in W fp32->bf16
// preconvert and stats zeroing (blocks 2500..2531).
__global__ __launch_bounds__(256) void esort_k(
    const int* __restrict__ ei, int* __restrict__ cursor,
    int* __restrict__ ssrc, const float* __restrict__ W1,
    const float* __restrict__ W2, unsigned short* __restrict__ wbf,
    float* __restrict__ stats) {
    int b = blockIdx.x;
    if (b >= 2500) {
        int i = (b - 2500) * 256 + threadIdx.x;   // 0..8191 float4 units
        if (b == 2500) {
            stats[threadIdx.x] = 0.f;
            stats[256 + threadIdx.x] = 0.f;
        }
        const float4* s4 = (i < 4096) ? (const float4*)W1 : (const float4*)W2;
        float4 v = s4[i & 4095];
        ushort4 u;
        u.x = f2bf(v.x); u.y = f2bf(v.y); u.z = f2bf(v.z); u.w = f2bf(v.w);
        ((ushort4*)wbf)[i] = u;
        return;
    }
    int e = b * 256 + threadIdx.x;
    int pos = atomicAdd(&cursor[ei[EE + e]], 1);
    ssrc[pos] = ei[e];
}

// ---------------------------------------------------------------------------
// aggregate + fuse: h[node] = bf16((1+eps)*x[node] + sum_{src in CSR} x[src])
// 32 lanes (float4) per node; launch_bounds(256,4) + 8-wide predicated
// unroll -> 8 row gathers in flight. Keep 12500 independent blocks (round-7
// lesson: grid-capping serialized the gather chains -> 220 GB/s).
// ---------------------------------------------------------------------------
__global__ __launch_bounds__(256, 4) void aggregate_k(
    const float4* __restrict__ x4, const int* __restrict__ ssrc,
    const int* __restrict__ offs, const int* __restrict__ deg,
    const float* __restrict__ epsp, ushort4* __restrict__ hout) {
    int tid = blockIdx.x * 256 + threadIdx.x;
    int node = tid >> 5, lane = tid & 31;
    if (node >= NN) return;
    int start = offs[node], d = deg[node];
    float ef = 1.0f + epsp[0];
    float4 v = x4[node * 32 + lane];
    float ax = ef * v.x, ay = ef * v.y, az = ef * v.z, aw = ef * v.w;
    for (int j = 0; j < d; j += 8) {
        int r = d - j;          // >= 1
        int b = start + j;
        int s0 = ssrc[b];
        int s1 = ssrc[b + ((r > 1) ? 1 : 0)];
        int s2 = ssrc[b + ((r > 2) ? 2 : 0)];
        int s3 = ssrc[b + ((r > 3) ? 3 : 0)];
        int s4i = ssrc[b + ((r > 4) ? 4 : 0)];
        int s5 = ssrc[b + ((r > 5) ? 5 : 0)];
        int s6 = ssrc[b + ((r > 6) ? 6 : 0)];
        int s7 = ssrc[b + ((r > 7) ? 7 : 0)];
        float4 x0 = x4[s0 * 32 + lane];
        float4 x1 = x4[s1 * 32 + lane];
        float4 x2 = x4[s2 * 32 + lane];
        float4 x3 = x4[s3 * 32 + lane];
        float4 x4v = x4[s4i * 32 + lane];
        float4 x5 = x4[s5 * 32 + lane];
        float4 x6 = x4[s6 * 32 + lane];
        float4 x7 = x4[s7 * 32 + lane];
        float m1 = (r > 1) ? 1.f : 0.f;
        float m2 = (r > 2) ? 1.f : 0.f;
        float m3 = (r > 3) ? 1.f : 0.f;
        float m4 = (r > 4) ? 1.f : 0.f;
        float m5 = (r > 5) ? 1.f : 0.f;
        float m6 = (r > 6) ? 1.f : 0.f;
        float m7 = (r > 7) ? 1.f : 0.f;
        ax += x0.x; ay += x0.y; az += x0.z; aw += x0.w;
        ax += m1 * x1.x; ay += m1 * x1.y; az += m1 * x1.z; aw += m1 * x1.w;
        ax += m2 * x2.x; ay += m2 * x2.y; az += m2 * x2.z; aw += m2 * x2.w;
        ax += m3 * x3.x; ay += m3 * x3.y; az += m3 * x3.z; aw += m3 * x3.w;
        ax += m4 * x4v.x; ay += m4 * x4v.y; az += m4 * x4v.z; aw += m4 * x4v.w;
        ax += m5 * x5.x; ay += m5 * x5.y; az += m5 * x5.z; aw += m5 * x5.w;
        ax += m6 * x6.x; ay += m6 * x6.y; az += m6 * x6.z; aw += m6 * x6.w;
        ax += m7 * x7.x; ay += m7 * x7.y; az += m7 * x7.z; aw += m7 * x7.w;
    }
    ushort4 u;
    u.x = f2bf(ax); u.y = f2bf(ay); u.z = f2bf(az); u.w = f2bf(aw);
    hout[node * 32 + lane] = u;
}

// ---------------------------------------------------------------------------
// Persistent-W GEMM + bias + BN-stat accumulation (round-6 verified body).
// Whole bf16 W in registers (32 x bf16x8); grid-stride over 16-row tiles,
// prefetch depth 1; epilogue staged through wave-private LDS for fully-
// covered 128B-line stores. FUSE_BN=1: BN(statsIn)+ReLU applied to fp32 yin
// in the loader (in-place y1->y2 safe: tile ownership by residue class).
// ---------------------------------------------------------------------------
template <int FUSE_BN>
__global__ __launch_bounds__(256, 2) void gin_gemm_k(
    const unsigned short* __restrict__ hin,
    const float* __restrict__ yin,
    const float* __restrict__ statsIn,
    const float* __restrict__ gmm,
    const float* __restrict__ bta,
    const unsigned short* __restrict__ Wbf, const float* __restrict__ bias,
    float* __restrict__ y, float* __restrict__ statsOut) {
    __shared__ __align__(16) float s_sum[128];
    __shared__ __align__(16) float s_sq[128];
    __shared__ __align__(16) float sc[128];
    __shared__ __align__(16) float sh[128];
    __shared__ __align__(16) float yst[4][16][132];  // per-wave tile, +4 pad

    const int tid = threadIdx.x;
    const int l = tid & 63, w = tid >> 6;
    const int m = l & 15, q = l >> 4;

    if (tid < 128) {
        s_sum[tid] = 0.f;
        s_sq[tid] = 0.f;
        if (FUSE_BN) {
            const float inv = 1.0f / (float)NN;
            float mean = statsIn[tid] * inv;
            float var = statsIn[128 + tid] * inv - mean * mean;
            float s = gmm[tid] * rsqrtf(var + 1e-5f);
            sc[tid] = s;
            sh[tid] = bta[tid] - mean * s;
        }
    }

    // --- whole W into registers, once per wave ---
    bf16x8 wf[8][4];
#pragma unroll
    for (int ct = 0; ct < 8; ++ct) {
        const unsigned short* wr = Wbf + (size_t)(ct * 16 + m) * 128 + q * 8;
#pragma unroll
        for (int kc = 0; kc < 4; ++kc) {
            BF8 t;
            t.i4 = *(const int4*)(wr + kc * 32);
            wf[ct][kc] = t.v;
        }
    }
    float bc[8];
#pragma unroll
    for (int ct = 0; ct < 8; ++ct) bc[ct] = bias[ct * 16 + m];

    float ps[8], pq[8];
#pragma unroll
    for (int ct = 0; ct < 8; ++ct) { ps[ct] = 0.f; pq[ct] = 0.f; }

    __syncthreads();  // s_sum/s_sq (and sc/sh) visible

    const int NT = NN / 16;              // 6250, exact
    const int stride = gridDim.x * 4;    // waves total
    int t = blockIdx.x * 4 + w;

    const unsigned short* abase = hin + (size_t)m * 128 + q * 8;
    const float* ybase = yin + (size_t)m * 128 + q * 8;

    int4 ra[4];      // FUSE_BN=0 prefetch
    float4 rf[8];    // FUSE_BN=1 prefetch
    if (t < NT) {
        if (FUSE_BN) {
            const float* yp = ybase + (size_t)t * (16 * 128);
#pragma unroll
            for (int i = 0; i < 8; ++i)
                rf[i] = *(const float4*)(yp + (i >> 1) * 32 + (i & 1) * 4);
        } else {
            const unsigned short* ap = abase + (size_t)t * (16 * 128);
#pragma unroll
            for (int kc = 0; kc < 4; ++kc) ra[kc] = *(const int4*)(ap + kc * 32);
        }
    }

    while (t < NT) {
        bf16x8 a[4];
#pragma unroll
        for (int kc = 0; kc < 4; ++kc) {
            if (FUSE_BN) {
                float4 v0 = rf[2 * kc], v1 = rf[2 * kc + 1];
                float4 s0 = *(const float4*)(sc + kc * 32 + q * 8);
                float4 s1 = *(const float4*)(sc + kc * 32 + q * 8 + 4);
                float4 h0 = *(const float4*)(sh + kc * 32 + q * 8);
                float4 h1 = *(const float4*)(sh + kc * 32 + q * 8 + 4);
                BF8 tt;
                tt.u[0] = f2bf(fmaxf(v0.x * s0.x + h0.x, 0.f));
                tt.u[1] = f2bf(fmaxf(v0.y * s0.y + h0.y, 0.f));
                tt.u[2] = f2bf(fmaxf(v0.z * s0.z + h0.z, 0.f));
                tt.u[3] = f2bf(fmaxf(v0.w * s0.w + h0.w, 0.f));
                tt.u[4] = f2bf(fmaxf(v1.x * s1.x + h1.x, 0.f));
                tt.u[5] = f2bf(fmaxf(v1.y * s1.y + h1.y, 0.f));
                tt.u[6] = f2bf(fmaxf(v1.z * s1.z + h1.z, 0.f));
                tt.u[7] = f2bf(fmaxf(v1.w * s1.w + h1.w, 0.f));
                a[kc] = tt.v;
            } else {
                BF8 tt;
                tt.i4 = ra[kc];
                a[kc] = tt.v;
            }
        }

        int tn = t + stride;
        if (tn < NT) {
            if (FUSE_BN) {
                const float* yp = ybase + (size_t)tn * (16 * 128);
#pragma unroll
                for (int i = 0; i < 8; ++i)
                    rf[i] = *(const float4*)(yp + (i >> 1) * 32 + (i & 1) * 4);
            } else {
                const unsigned short* ap = abase + (size_t)tn * (16 * 128);
#pragma unroll
                for (int kc = 0; kc < 4; ++kc) ra[kc] = *(const int4*)(ap + kc * 32);
            }
        }

        floatx4 acc[8];
#pragma unroll
        for (int ct = 0; ct < 8; ++ct) acc[ct] = (floatx4)0.0f;
#pragma unroll
        for (int kc = 0; kc < 4; ++kc)
#pragma unroll
            for (int ct = 0; ct < 8; ++ct)
                acc[ct] = __builtin_amdgcn_mfma_f32_16x16x32_bf16(a[kc], wf[ct][kc], acc[ct], 0, 0, 0);

        // epilogue: bias + stats, stage tile in wave-private LDS, then store
        // full float4 rows (lanes 0-31 = 512B contiguous, full 128B lines)
#pragma unroll
        for (int ct = 0; ct < 8; ++ct) {
#pragma unroll
            for (int i = 0; i < 4; ++i) {
                float yv = acc[ct][i] + bc[ct];
                yst[w][q * 4 + i][ct * 16 + m] = yv;
                ps[ct] += yv;
                pq[ct] += yv * yv;
            }
        }
        asm volatile("s_waitcnt lgkmcnt(0)" ::: "memory");
        float* yb = y + (size_t)t * (16 * 128);
#pragma unroll
        for (int it = 0; it < 8; ++it) {
            int f4 = it * 64 + l;
            int row = f4 >> 5, c4 = f4 & 31;
            float4 vv = *(const float4*)&yst[w][row][c4 * 4];
            *(float4*)(yb + row * 128 + c4 * 4) = vv;
        }
        t = tn;
    }

    // flush register stats: LDS reduce, then 2 global atomics per column
#pragma unroll
    for (int ct = 0; ct < 8; ++ct) {
        atomicAdd(&s_sum[ct * 16 + m], ps[ct]);
        atomicAdd(&s_sq[ct * 16 + m], pq[ct]);
    }
    __syncthreads();
    if (tid < 128) {
        unsafeAtomicAdd(&statsOut[tid], s_sum[tid]);
        unsafeAtomicAdd(&statsOut[128 + tid], s_sq[tid]);
    }
}

// ---------------------------------------------------------------------------
// BN(train, biased var) + ReLU, fp32 in place (final layer only).
// ---------------------------------------------------------------------------
__global__ __launch_bounds__(256) void bn_relu_k(
    const float* __restrict__ y, const float* __restrict__ stats,
    const float* __restrict__ g, const float* __restrict__ beta,
    float* __restrict__ outf) {
    __shared__ __align__(16) float sc[128];
    __shared__ __align__(16) float sh[128];
    int t = threadIdx.x;
    if (t < 128) {
        const float inv = 1.0f / (float)NN;
        float mean = stats[t] * inv;
        float var = stats[128 + t] * inv - mean * mean;
        float s = g[t] * rsqrtf(var + 1e-5f);
        sc[t] = s;
        sh[t] = beta[t] - mean * s;
    }
    __syncthreads();
    const int total4 = NN * 32;
    const float4* y4 = (const float4*)y;
    for (int i = blockIdx.x * 256 + t; i < total4; i += gridDim.x * 256) {
        int c4 = i & 31;
        float4 v = y4[i];
        float4 s = ((const float4*)sc)[c4];
        float4 b = ((const float4*)sh)[c4];
        float r0 = fmaxf(v.x * s.x + b.x, 0.f);
        float r1 = fmaxf(v.y * s.y + b.y, 0.f);
        float r2 = fmaxf(v.z * s.z + b.z, 0.f);
        float r3 = fmaxf(v.w * s.w + b.w, 0.f);
        ((float4*)outf)[i] = make_float4(r0, r1, r2, r3);
    }
}

// ---------------------------------------------------------------------------
extern "C" void kernel_launch(void* const* d_in, const int* in_sizes, int n_in,
                              void* d_out, int out_size, void* d_ws, size_t ws_size,
                              hipStream_t stream) {
    const float* x   = (const float*)d_in[0];
    const int* ei    = (const int*)d_in[1];   // int64 in ref -> int32 from harness
    const float* eps = (const float*)d_in[2];
    const float* W1  = (const float*)d_in[3];
    const float* b1  = (const float*)d_in[4];
    const float* g1  = (const float*)d_in[5];
    const float* be1 = (const float*)d_in[6];
    const float* W2  = (const float*)d_in[7];
    const float* b2  = (const float*)d_in[8];
    const float* g2  = (const float*)d_in[9];
    const float* be2 = (const float*)d_in[10];
    float* out = (float*)d_out;

    // Workspace (~29.6 MB):
    // [deg NPAD][descr 512][offs NPAD][cursor NPAD][ssrc EE+256]
    // [hbuf bf16 25.6MB][stats 512f][wbf 2*128*128 bf16]
    int* deg            = (int*)d_ws;
    unsigned int* descr = (unsigned int*)(deg + NPAD);      // 512 (>= NCHUNK)
    int* offs           = (int*)(descr + 512);
    int* cursor         = offs + NPAD;
    int* ssrc           = cursor + NPAD;
    unsigned short* hbuf = (unsigned short*)(ssrc + EE + 256);
    float* stats        = (float*)(hbuf + (size_t)NN * DD);
    unsigned short* wbf = (unsigned short*)(stats + 512);

    // one memset covers deg + lookback descriptors (adjacent)
    hipMemsetAsync(deg, 0, (NPAD + 512) * sizeof(int), stream);

    hist_k<<<(EE + 255) / 256, 256, 0, stream>>>(ei, deg);
    scanlb_k<<<NCHUNK, 256, 0, stream>>>(deg, descr, offs, cursor);
    esort_k<<<2500 + 32, 256, 0, stream>>>(ei, cursor, ssrc, W1, W2, wbf, stats);
    aggregate_k<<<(NN * 32 + 255) / 256, 256, 0, stream>>>(
        (const float4*)x, ssrc, offs, deg, eps, (ushort4*)hbuf);

    const int gblocks = 512;  // ~2 blocks/CU, persistent grid-stride
    gin_gemm_k<0><<<gblocks, 256, 0, stream>>>(
        hbuf, nullptr, nullptr, nullptr, nullptr, wbf, b1, out, stats);
    gin_gemm_k<1><<<gblocks, 256, 0, stream>>>(
        nullptr, out, stats, g1, be1, wbf + 16384, b2, out, stats + 256);
    bn_relu_k<<<4096, 256, 0, stream>>>(out, stats + 256, g2, be2, out);
}

// Round 11
// 318.851 us; speedup vs baseline: 3.0292x; 1.0359x over previous
//
#include <hip/hip_runtime.h>

#define NN 100000
#define DD 128
#define EE 640000
#define NPAD 100352   // NN rounded up to 256 multiple
#define NCHUNK 391    // (NN+255)/256

typedef __bf16 bf16x8 __attribute__((ext_vector_type(8)));
typedef float floatx4 __attribute__((ext_vector_type(4)));

union BF8 {
    bf16x8 v;
    unsigned short u[8];
    int4 i4;
};

__device__ __forceinline__ unsigned short f2bf(float f) {
    unsigned int u = __float_as_uint(f);
    u += 0x7FFF + ((u >> 16) & 1);   // round-to-nearest-even
    return (unsigned short)(u >> 16);
}

__device__ __forceinline__ float bf2f(unsigned short h) {
    return __uint_as_float(((unsigned int)h) << 16);
}

// ---------------------------------------------------------------------------
// CSR build (all-regular launches; round-10 lesson: do NOT mix cooperative
// and regular kernels under graph capture — ordering broke, absmax 6.75):
//   hist -> scanlb (wave-parallel decoupled lookback) -> esort(+wconv+zero)
// ---------------------------------------------------------------------------
__global__ __launch_bounds__(256) void hist_k(const int* __restrict__ ei,
                                              int* __restrict__ deg) {
    int e = blockIdx.x * 256 + threadIdx.x;
    if (e < EE) atomicAdd(&deg[ei[EE + e]], 1);
}

// Single-pass exclusive scan over NN degrees. descr[c]: bits31..30 flag
// (0=empty, 1=aggregate, 2=inclusive-prefix), bits29..0 sum (EE < 2^30).
// Wave 0's 64 lanes read 64 predecessor descriptors per round (round-8
// lesson: single-thread lookback = 106us serial chain; this is ~5us).
__global__ __launch_bounds__(256) void scanlb_k(
    const int* __restrict__ deg, unsigned int* __restrict__ descr,
    int* __restrict__ offs, int* __restrict__ cursor) {
    __shared__ int s[256];
    __shared__ int sbase;
    const int c = blockIdx.x, t = threadIdx.x;
    int g = c * 256 + t;
    int v = (g < NN) ? deg[g] : 0;
    s[t] = v;
    __syncthreads();
    for (int off = 1; off < 256; off <<= 1) {
        int u = (t >= off) ? s[t - off] : 0;
        __syncthreads();
        s[t] += u;
        __syncthreads();
    }
    const int total = s[255];
    if (c == 0) {
        if (t == 0) {
            __hip_atomic_store(&descr[0], (2u << 30) | (unsigned)total,
                               __ATOMIC_RELEASE, __HIP_MEMORY_SCOPE_AGENT);
            sbase = 0;
        }
    } else if (t < 64) {
        if (t == 0)
            __hip_atomic_store(&descr[c], (1u << 30) | (unsigned)total,
                               __ATOMIC_RELEASE, __HIP_MEMORY_SCOPE_AGENT);
        int acc = 0;
        int base = c - 1;              // lane l inspects block (base - l)
        while (true) {
            int p = base - t;
            unsigned st = (p >= 0)
                ? __hip_atomic_load(&descr[p], __ATOMIC_ACQUIRE,
                                    __HIP_MEMORY_SCOPE_AGENT)
                : (2u << 30);          // virtual block -1: prefix 0
            unsigned fl = st >> 30;
            unsigned long long b2 = __ballot(fl == 2u);
            unsigned long long b0 = __ballot(fl == 0u);
            int l2 = b2 ? (__ffsll(b2) - 1) : 64;   // nearest inclusive-prefix
            int l0 = b0 ? (__ffsll(b0) - 1) : 64;   // nearest unpublished
            if (l0 < l2) continue;     // blocked by an empty slot: retry
            unsigned contrib = (t <= l2) ? (st & 0x3FFFFFFFu) : 0u;
#pragma unroll
            for (int o2 = 32; o2 > 0; o2 >>= 1)
                contrib += __shfl_down(contrib, o2, 64);
            contrib = __shfl(contrib, 0, 64);
            acc += (int)contrib;
            if (l2 < 64) break;        // absorbed an inclusive prefix
            base -= 64;                // all aggregates: step back a window
        }
        if (t == 0) {
            sbase = acc;
            __hip_atomic_store(&descr[c], (2u << 30) | (unsigned)(acc + total),
                               __ATOMIC_RELEASE, __HIP_MEMORY_SCOPE_AGENT);
        }
    }
    __syncthreads();
    if (g < NN) {
        int o = sbase + s[t] - v;   // exclusive prefix
        offs[g] = o;
        cursor[g] = o;
    }
}

// esort (blocks 0..2499; EE = 2500*256 exactly) + folded-in W fp32->bf16
// preconvert and stats zeroing (blocks 2500..2531).
__global__ __launch_bounds__(256) void esort_k(
    const int* __restrict__ ei, int* __restrict__ cursor,
    int* __restrict__ ssrc, const float* __restrict__ W1,
    const float* __restrict__ W2, unsigned short* __restrict__ wbf,
    float* __restrict__ stats) {
    int b = blockIdx.x;
    if (b >= 2500) {
        int i = (b - 2500) * 256 + threadIdx.x;   // 0..8191 float4 units
        if (b == 2500) {
            stats[threadIdx.x] = 0.f;
            stats[256 + threadIdx.x] = 0.f;
        }
        const float4* s4 = (i < 4096) ? (const float4*)W1 : (const float4*)W2;
        float4 v = s4[i & 4095];
        ushort4 u;
        u.x = f2bf(v.x); u.y = f2bf(v.y); u.z = f2bf(v.z); u.w = f2bf(v.w);
        ((ushort4*)wbf)[i] = u;
        return;
    }
    int e = b * 256 + threadIdx.x;
    int pos = atomicAdd(&cursor[ei[EE + e]], 1);
    ssrc[pos] = ei[e];
}

// ---------------------------------------------------------------------------
// aggregate + fuse: h[node] = bf16((1+eps)*x[node] + sum_{src in CSR} x[src])
// 32 lanes (float4) per node; 8-wide predicated gather unroll; 12500
// independent blocks (round-7 lesson: grid-capping serialized the chains).
// ---------------------------------------------------------------------------
__global__ __launch_bounds__(256, 4) void aggregate_k(
    const float4* __restrict__ x4, const int* __restrict__ ssrc,
    const int* __restrict__ offs, const int* __restrict__ deg,
    const float* __restrict__ epsp, ushort4* __restrict__ hout) {
    int tid = blockIdx.x * 256 + threadIdx.x;
    int node = tid >> 5, lane = tid & 31;
    if (node >= NN) return;
    int start = offs[node], d = deg[node];
    float ef = 1.0f + epsp[0];
    float4 v = x4[node * 32 + lane];
    float ax = ef * v.x, ay = ef * v.y, az = ef * v.z, aw = ef * v.w;
    for (int j = 0; j < d; j += 8) {
        int r = d - j;          // >= 1
        int b = start + j;
        int s0 = ssrc[b];
        int s1 = ssrc[b + ((r > 1) ? 1 : 0)];
        int s2 = ssrc[b + ((r > 2) ? 2 : 0)];
        int s3 = ssrc[b + ((r > 3) ? 3 : 0)];
        int s4i = ssrc[b + ((r > 4) ? 4 : 0)];
        int s5 = ssrc[b + ((r > 5) ? 5 : 0)];
        int s6 = ssrc[b + ((r > 6) ? 6 : 0)];
        int s7 = ssrc[b + ((r > 7) ? 7 : 0)];
        float4 x0 = x4[s0 * 32 + lane];
        float4 x1 = x4[s1 * 32 + lane];
        float4 x2 = x4[s2 * 32 + lane];
        float4 x3 = x4[s3 * 32 + lane];
        float4 x4v = x4[s4i * 32 + lane];
        float4 x5 = x4[s5 * 32 + lane];
        float4 x6 = x4[s6 * 32 + lane];
        float4 x7 = x4[s7 * 32 + lane];
        float m1 = (r > 1) ? 1.f : 0.f;
        float m2 = (r > 2) ? 1.f : 0.f;
        float m3 = (r > 3) ? 1.f : 0.f;
        float m4 = (r > 4) ? 1.f : 0.f;
        float m5 = (r > 5) ? 1.f : 0.f;
        float m6 = (r > 6) ? 1.f : 0.f;
        float m7 = (r > 7) ? 1.f : 0.f;
        ax += x0.x; ay += x0.y; az += x0.z; aw += x0.w;
        ax += m1 * x1.x; ay += m1 * x1.y; az += m1 * x1.z; aw += m1 * x1.w;
        ax += m2 * x2.x; ay += m2 * x2.y; az += m2 * x2.z; aw += m2 * x2.w;
        ax += m3 * x3.x; ay += m3 * x3.y; az += m3 * x3.z; aw += m3 * x3.w;
        ax += m4 * x4v.x; ay += m4 * x4v.y; az += m4 * x4v.z; aw += m4 * x4v.w;
        ax += m5 * x5.x; ay += m5 * x5.y; az += m5 * x5.z; aw += m5 * x5.w;
        ax += m6 * x6.x; ay += m6 * x6.y; az += m6 * x6.z; aw += m6 * x6.w;
        ax += m7 * x7.x; ay += m7 * x7.y; az += m7 * x7.z; aw += m7 * x7.w;
    }
    ushort4 u;
    u.x = f2bf(ax); u.y = f2bf(ay); u.z = f2bf(az); u.w = f2bf(aw);
    hout[node * 32 + lane] = u;
}

// ---------------------------------------------------------------------------
// Persistent-W GEMM + bias + BN-stat accumulation.
// Whole bf16 W in registers (32 x bf16x8); grid-stride over 16-row tiles,
// prefetch depth 1; epilogue staged through wave-private LDS for fully-
// covered 128B-line stores. A input is ALWAYS bf16 (int4 loads).
// FUSE_BN=1: BN(statsIn,gmm,bta)+ReLU applied to the bf16 A in the loader.
// OUT_BF16=1: y stored as bf16 (saves half the write traffic; stats are
// still accumulated from the exact fp32 accumulators).
// ---------------------------------------------------------------------------
template <int FUSE_BN, int OUT_BF16>
__global__ __launch_bounds__(256, 2) void gin_gemm_k(
    const unsigned short* __restrict__ hin,
    const float* __restrict__ statsIn,
    const float* __restrict__ gmm,
    const float* __restrict__ bta,
    const unsigned short* __restrict__ Wbf, const float* __restrict__ bias,
    float* __restrict__ yf, unsigned short* __restrict__ yh,
    float* __restrict__ statsOut) {
    __shared__ __align__(16) float s_sum[128];
    __shared__ __align__(16) float s_sq[128];
    __shared__ __align__(16) float sc[128];
    __shared__ __align__(16) float sh[128];
    __shared__ __align__(16) float yst[4][16][132];  // fp32 tile (+4 pad)

    const int tid = threadIdx.x;
    const int l = tid & 63, w = tid >> 6;
    const int m = l & 15, q = l >> 4;

    if (tid < 128) {
        s_sum[tid] = 0.f;
        s_sq[tid] = 0.f;
        if (FUSE_BN) {
            const float inv = 1.0f / (float)NN;
            float mean = statsIn[tid] * inv;
            float var = statsIn[128 + tid] * inv - mean * mean;
            float s = gmm[tid] * rsqrtf(var + 1e-5f);
            sc[tid] = s;
            sh[tid] = bta[tid] - mean * s;
        }
    }

    // --- whole W into registers, once per wave ---
    bf16x8 wf[8][4];
#pragma unroll
    for (int ct = 0; ct < 8; ++ct) {
        const unsigned short* wr = Wbf + (size_t)(ct * 16 + m) * 128 + q * 8;
#pragma unroll
        for (int kc = 0; kc < 4; ++kc) {
            BF8 t;
            t.i4 = *(const int4*)(wr + kc * 32);
            wf[ct][kc] = t.v;
        }
    }
    float bc[8];
#pragma unroll
    for (int ct = 0; ct < 8; ++ct) bc[ct] = bias[ct * 16 + m];

    float ps[8], pq[8];
#pragma unroll
    for (int ct = 0; ct < 8; ++ct) { ps[ct] = 0.f; pq[ct] = 0.f; }

    __syncthreads();  // s_sum/s_sq (and sc/sh) visible

    const int NT = NN / 16;              // 6250, exact
    const int stride = gridDim.x * 4;    // waves total
    int t = blockIdx.x * 4 + w;

    const unsigned short* abase = hin + (size_t)m * 128 + q * 8;

    int4 ra[4];
    if (t < NT) {
        const unsigned short* ap = abase + (size_t)t * (16 * 128);
#pragma unroll
        for (int kc = 0; kc < 4; ++kc) ra[kc] = *(const int4*)(ap + kc * 32);
    }

    // bf16 store path aliases this wave's fp32 tile region: 16 x [144] ushort
    // (row stride 288B: rows land on disjoint 8-bank groups; only the free
    // 2-way ushort pairing remains). 4608B < 8448B wave region.
    unsigned short* ysth = (unsigned short*)&yst[w][0][0];

    while (t < NT) {
        // consume prefetched raw bf16 A into fragment regs
        bf16x8 a[4];
#pragma unroll
        for (int kc = 0; kc < 4; ++kc) {
            if (FUSE_BN) {
                BF8 raw;
                raw.i4 = ra[kc];
                const float* scp = sc + kc * 32 + q * 8;
                const float* shp = sh + kc * 32 + q * 8;
                float4 s0 = *(const float4*)scp;
                float4 s1 = *(const float4*)(scp + 4);
                float4 h0 = *(const float4*)shp;
                float4 h1 = *(const float4*)(shp + 4);
                BF8 tt;
                tt.u[0] = f2bf(fmaxf(bf2f(raw.u[0]) * s0.x + h0.x, 0.f));
                tt.u[1] = f2bf(fmaxf(bf2f(raw.u[1]) * s0.y + h0.y, 0.f));
                tt.u[2] = f2bf(fmaxf(bf2f(raw.u[2]) * s0.z + h0.z, 0.f));
                tt.u[3] = f2bf(fmaxf(bf2f(raw.u[3]) * s0.w + h0.w, 0.f));
                tt.u[4] = f2bf(fmaxf(bf2f(raw.u[4]) * s1.x + h1.x, 0.f));
                tt.u[5] = f2bf(fmaxf(bf2f(raw.u[5]) * s1.y + h1.y, 0.f));
                tt.u[6] = f2bf(fmaxf(bf2f(raw.u[6]) * s1.z + h1.z, 0.f));
                tt.u[7] = f2bf(fmaxf(bf2f(raw.u[7]) * s1.w + h1.w, 0.f));
                a[kc] = tt.v;
            } else {
                BF8 tt;
                tt.i4 = ra[kc];
                a[kc] = tt.v;
            }
        }

        // issue next tile's loads before compute (hidden under MFMA+stores)
        int tn = t + stride;
        if (tn < NT) {
            const unsigned short* ap = abase + (size_t)tn * (16 * 128);
#pragma unroll
            for (int kc = 0; kc < 4; ++kc) ra[kc] = *(const int4*)(ap + kc * 32);
        }

        floatx4 acc[8];
#pragma unroll
        for (int ct = 0; ct < 8; ++ct) acc[ct] = (floatx4)0.0f;
#pragma unroll
        for (int kc = 0; kc < 4; ++kc)
#pragma unroll
            for (int ct = 0; ct < 8; ++ct)
                acc[ct] = __builtin_amdgcn_mfma_f32_16x16x32_bf16(a[kc], wf[ct][kc], acc[ct], 0, 0, 0);

        // epilogue: bias + stats (exact fp32), stage tile in wave-private
        // LDS, then store full contiguous rows (fully covered 128B lines)
#pragma unroll
        for (int ct = 0; ct < 8; ++ct) {
#pragma unroll
            for (int i = 0; i < 4; ++i) {
                float yv = acc[ct][i] + bc[ct];
                if (OUT_BF16) {
                    ysth[(q * 4 + i) * 144 + ct * 16 + m] = f2bf(yv);
                } else {
                    yst[w][q * 4 + i][ct * 16 + m] = yv;
                }
                ps[ct] += yv;
                pq[ct] += yv * yv;
            }
        }
        asm volatile("s_waitcnt lgkmcnt(0)" ::: "memory");
        if (OUT_BF16) {
            unsigned short* yb = yh + (size_t)t * (16 * 128);
#pragma unroll
            for (int it = 0; it < 4; ++it) {
                int f = it * 64 + l;
                int row = f >> 4, c8 = f & 15;   // 16 x 16B units per row
                int4 vv = *(const int4*)&ysth[row * 144 + c8 * 8];
                *(int4*)(yb + row * 128 + c8 * 8) = vv;
            }
        } else {
            float* yb = yf + (size_t)t * (16 * 128);
#pragma unroll
            for (int it = 0; it < 8; ++it) {
                int f4 = it * 64 + l;
                int row = f4 >> 5, c4 = f4 & 31;
                float4 vv = *(const float4*)&yst[w][row][c4 * 4];
                *(float4*)(yb + row * 128 + c4 * 4) = vv;
            }
        }
        t = tn;
    }

    // flush register stats: LDS reduce, then 2 global atomics per column
#pragma unroll
    for (int ct = 0; ct < 8; ++ct) {
        atomicAdd(&s_sum[ct * 16 + m], ps[ct]);
        atomicAdd(&s_sq[ct * 16 + m], pq[ct]);
    }
    __syncthreads();
    if (tid < 128) {
        unsafeAtomicAdd(&statsOut[tid], s_sum[tid]);
        unsafeAtomicAdd(&statsOut[128 + tid], s_sq[tid]);
    }
}

// ---------------------------------------------------------------------------
// BN(train, biased var) + ReLU, fp32 in place (final layer only).
// ---------------------------------------------------------------------------
__global__ __launch_bounds__(256) void bn_relu_k(
    const float* __restrict__ y, const float* __restrict__ stats,
    const float* __restrict__ g, const float* __restrict__ beta,
    float* __restrict__ outf) {
    __shared__ __align__(16) float sc[128];
    __shared__ __align__(16) float sh[128];
    int t = threadIdx.x;
    if (t < 128) {
        const float inv = 1.0f / (float)NN;
        float mean = stats[t] * inv;
        float var = stats[128 + t] * inv - mean * mean;
        float s = g[t] * rsqrtf(var + 1e-5f);
        sc[t] = s;
        sh[t] = beta[t] - mean * s;
    }
    __syncthreads();
    const int total4 = NN * 32;
    const float4* y4 = (const float4*)y;
    for (int i = blockIdx.x * 256 + t; i < total4; i += gridDim.x * 256) {
        int c4 = i & 31;
        float4 v = y4[i];
        float4 s = ((const float4*)sc)[c4];
        float4 b = ((const float4*)sh)[c4];
        float r0 = fmaxf(v.x * s.x + b.x, 0.f);
        float r1 = fmaxf(v.y * s.y + b.y, 0.f);
        float r2 = fmaxf(v.z * s.z + b.z, 0.f);
        float r3 = fmaxf(v.w * s.w + b.w, 0.f);
        ((float4*)outf)[i] = make_float4(r0, r1, r2, r3);
    }
}

// ---------------------------------------------------------------------------
extern "C" void kernel_launch(void* const* d_in, const int* in_sizes, int n_in,
                              void* d_out, int out_size, void* d_ws, size_t ws_size,
                              hipStream_t stream) {
    const float* x   = (const float*)d_in[0];
    const int* ei    = (const int*)d_in[1];   // int64 in ref -> int32 from harness
    const float* eps = (const float*)d_in[2];
    const float* W1  = (const float*)d_in[3];
    const float* b1  = (const float*)d_in[4];
    const float* g1  = (const float*)d_in[5];
    const float* be1 = (const float*)d_in[6];
    const float* W2  = (const float*)d_in[7];
    const float* b2  = (const float*)d_in[8];
    const float* g2  = (const float*)d_in[9];
    const float* be2 = (const float*)d_in[10];
    float* out = (float*)d_out;

    // Workspace (~55.1 MB; ws >= 77 MB established in round 2):
    // [deg NPAD][descr 512][offs NPAD][cursor NPAD][ssrc EE+256]
    // [hbuf bf16 25.6MB][y1bf bf16 25.6MB][stats 512f][wbf 2*128*128 bf16]
    int* deg            = (int*)d_ws;
    unsigned int* descr = (unsigned int*)(deg + NPAD);      // 512 (>= NCHUNK)
    int* offs           = (int*)(descr + 512);
    int* cursor         = offs + NPAD;
    int* ssrc           = cursor + NPAD;
    unsigned short* hbuf = (unsigned short*)(ssrc + EE + 256);
    unsigned short* y1bf = hbuf + (size_t)NN * DD;
    float* stats        = (float*)(y1bf + (size_t)NN * DD);
    unsigned short* wbf = (unsigned short*)(stats + 512);

    // one memset covers deg + lookback descriptors (adjacent)
    hipMemsetAsync(deg, 0, (NPAD + 512) * sizeof(int), stream);

    hist_k<<<(EE + 255) / 256, 256, 0, stream>>>(ei, deg);
    scanlb_k<<<NCHUNK, 256, 0, stream>>>(deg, descr, offs, cursor);
    esort_k<<<2500 + 32, 256, 0, stream>>>(ei, cursor, ssrc, W1, W2, wbf, stats);
    aggregate_k<<<(NN * 32 + 255) / 256, 256, 0, stream>>>(
        (const float4*)x, ssrc, offs, deg, eps, (ushort4*)hbuf);

    const int gblocks = 512;  // ~2 blocks/CU, persistent grid-stride
    // gemm1: h(bf16) @ W1^T -> y1 as bf16 (+exact fp32 stats1)
    gin_gemm_k<0, 1><<<gblocks, 256, 0, stream>>>(
        hbuf, nullptr, nullptr, nullptr, wbf, b1, nullptr, y1bf, stats);
    // gemm2: BN1(y1bf)+ReLU in loader, @ W2^T -> y2 fp32 to out (+stats2)
    gin_gemm_k<1, 0><<<gblocks, 256, 0, stream>>>(
        y1bf, stats, g1, be1, wbf + 16384, b2, out, nullptr, stats + 256);
    bn_relu_k<<<4096, 256, 0, stream>>>(out, stats + 256, g2, be2, out);
}

// Round 12
// 309.170 us; speedup vs baseline: 3.1241x; 1.0313x over previous
//
#include <hip/hip_runtime.h>

#define NN 100000
#define DD 128
#define EE 640000
#define NPAD 100352   // NN rounded up to 256 multiple
#define NCHUNK 391    // (NN+255)/256

typedef __bf16 bf16x8 __attribute__((ext_vector_type(8)));
typedef float floatx4 __attribute__((ext_vector_type(4)));

union BF8 {
    bf16x8 v;
    unsigned short u[8];
    int4 i4;
};

__device__ __forceinline__ unsigned short f2bf(float f) {
    unsigned int u = __float_as_uint(f);
    u += 0x7FFF + ((u >> 16) & 1);   // round-to-nearest-even
    return (unsigned short)(u >> 16);
}

__device__ __forceinline__ float bf2f(unsigned short h) {
    return __uint_as_float(((unsigned int)h) << 16);
}

// ---------------------------------------------------------------------------
// hist (blocks 0..2499, EE = 2500*256 exactly) + folded x fp32->bf16 convert
// (blocks 2500..14999: 3.2M float4 units). The bf16 x copy halves the
// aggregate gather row size (512B -> 256B = 2 lines) and halves the gathered
// working set (51.2 -> 25.6 MB) -> higher L2 hit rate. Rounds 4-11 showed
// aggregate pinned at ~56us across all ILP variants = memory-system ceiling;
// traffic reduction is the only remaining lever there.
// ---------------------------------------------------------------------------
__global__ __launch_bounds__(256) void hist_k(const int* __restrict__ ei,
                                              int* __restrict__ deg,
                                              const float4* __restrict__ x4,
                                              ushort4* __restrict__ xbf) {
    int b = blockIdx.x;
    if (b >= 2500) {
        int i = (b - 2500) * 256 + threadIdx.x;   // 0..3,199,999
        float4 v = x4[i];
        ushort4 u;
        u.x = f2bf(v.x); u.y = f2bf(v.y); u.z = f2bf(v.z); u.w = f2bf(v.w);
        xbf[i] = u;
        return;
    }
    int e = b * 256 + threadIdx.x;                // < EE exactly
    atomicAdd(&deg[ei[EE + e]], 1);
}

// Single-pass exclusive scan over NN degrees. descr[c]: bits31..30 flag
// (0=empty, 1=aggregate, 2=inclusive-prefix), bits29..0 sum (EE < 2^30).
// Wave 0's 64 lanes read 64 predecessor descriptors per round (round-8
// lesson: single-thread lookback = 106us serial chain; this is ~5us).
__global__ __launch_bounds__(256) void scanlb_k(
    const int* __restrict__ deg, unsigned int* __restrict__ descr,
    int* __restrict__ offs, int* __restrict__ cursor) {
    __shared__ int s[256];
    __shared__ int sbase;
    const int c = blockIdx.x, t = threadIdx.x;
    int g = c * 256 + t;
    int v = (g < NN) ? deg[g] : 0;
    s[t] = v;
    __syncthreads();
    for (int off = 1; off < 256; off <<= 1) {
        int u = (t >= off) ? s[t - off] : 0;
        __syncthreads();
        s[t] += u;
        __syncthreads();
    }
    const int total = s[255];
    if (c == 0) {
        if (t == 0) {
            __hip_atomic_store(&descr[0], (2u << 30) | (unsigned)total,
                               __ATOMIC_RELEASE, __HIP_MEMORY_SCOPE_AGENT);
            sbase = 0;
        }
    } else if (t < 64) {
        if (t == 0)
            __hip_atomic_store(&descr[c], (1u << 30) | (unsigned)total,
                               __ATOMIC_RELEASE, __HIP_MEMORY_SCOPE_AGENT);
        int acc = 0;
        int base = c - 1;              // lane l inspects block (base - l)
        while (true) {
            int p = base - t;
            unsigned st = (p >= 0)
                ? __hip_atomic_load(&descr[p], __ATOMIC_ACQUIRE,
                                    __HIP_MEMORY_SCOPE_AGENT)
                : (2u << 30);          // virtual block -1: prefix 0
            unsigned fl = st >> 30;
            unsigned long long b2 = __ballot(fl == 2u);
            unsigned long long b0 = __ballot(fl == 0u);
            int l2 = b2 ? (__ffsll(b2) - 1) : 64;   // nearest inclusive-prefix
            int l0 = b0 ? (__ffsll(b0) - 1) : 64;   // nearest unpublished
            if (l0 < l2) continue;     // blocked by an empty slot: retry
            unsigned contrib = (t <= l2) ? (st & 0x3FFFFFFFu) : 0u;
#pragma unroll
            for (int o2 = 32; o2 > 0; o2 >>= 1)
                contrib += __shfl_down(contrib, o2, 64);
            contrib = __shfl(contrib, 0, 64);
            acc += (int)contrib;
            if (l2 < 64) break;        // absorbed an inclusive prefix
            base -= 64;                // all aggregates: step back a window
        }
        if (t == 0) {
            sbase = acc;
            __hip_atomic_store(&descr[c], (2u << 30) | (unsigned)(acc + total),
                               __ATOMIC_RELEASE, __HIP_MEMORY_SCOPE_AGENT);
        }
    }
    __syncthreads();
    if (g < NN) {
        int o = sbase + s[t] - v;   // exclusive prefix
        offs[g] = o;
        cursor[g] = o;
    }
}

// esort (blocks 0..2499) + folded-in W fp32->bf16 preconvert and stats
// zeroing (blocks 2500..2531).
__global__ __launch_bounds__(256) void esort_k(
    const int* __restrict__ ei, int* __restrict__ cursor,
    int* __restrict__ ssrc, const float* __restrict__ W1,
    const float* __restrict__ W2, unsigned short* __restrict__ wbf,
    float* __restrict__ stats) {
    int b = blockIdx.x;
    if (b >= 2500) {
        int i = (b - 2500) * 256 + threadIdx.x;   // 0..8191 float4 units
        if (b == 2500) {
            stats[threadIdx.x] = 0.f;
            stats[256 + threadIdx.x] = 0.f;
        }
        const float4* s4 = (i < 4096) ? (const float4*)W1 : (const float4*)W2;
        float4 v = s4[i & 4095];
        ushort4 u;
        u.x = f2bf(v.x); u.y = f2bf(v.y); u.z = f2bf(v.z); u.w = f2bf(v.w);
        ((ushort4*)wbf)[i] = u;
        return;
    }
    int e = b * 256 + threadIdx.x;
    int pos = atomicAdd(&cursor[ei[EE + e]], 1);
    ssrc[pos] = ei[e];
}

// ---------------------------------------------------------------------------
// aggregate + fuse: h[node] = bf16((1+eps)*x[node] + sum_{src in CSR} x[src])
// Gathers from the bf16 x copy: 256B rows (2 lines), lane = ushort4 (8B).
// 8-wide predicated unroll; 12500 independent blocks (round-7 lesson:
// grid-capping serialized the chains). fp32 accumulation.
// ---------------------------------------------------------------------------
__global__ __launch_bounds__(256, 4) void aggregate_k(
    const ushort4* __restrict__ xb, const int* __restrict__ ssrc,
    const int* __restrict__ offs, const int* __restrict__ deg,
    const float* __restrict__ epsp, ushort4* __restrict__ hout) {
    int tid = blockIdx.x * 256 + threadIdx.x;
    int node = tid >> 5, lane = tid & 31;
    if (node >= NN) return;
    int start = offs[node], d = deg[node];
    float ef = 1.0f + epsp[0];
    ushort4 ov = xb[node * 32 + lane];
    float ax = ef * bf2f(ov.x), ay = ef * bf2f(ov.y);
    float az = ef * bf2f(ov.z), aw = ef * bf2f(ov.w);
    for (int j = 0; j < d; j += 8) {
        int r = d - j;          // >= 1
        int b = start + j;
        int s0 = ssrc[b];
        int s1 = ssrc[b + ((r > 1) ? 1 : 0)];
        int s2 = ssrc[b + ((r > 2) ? 2 : 0)];
        int s3 = ssrc[b + ((r > 3) ? 3 : 0)];
        int s4i = ssrc[b + ((r > 4) ? 4 : 0)];
        int s5 = ssrc[b + ((r > 5) ? 5 : 0)];
        int s6 = ssrc[b + ((r > 6) ? 6 : 0)];
        int s7 = ssrc[b + ((r > 7) ? 7 : 0)];
        ushort4 x0 = xb[s0 * 32 + lane];
        ushort4 x1 = xb[s1 * 32 + lane];
        ushort4 x2 = xb[s2 * 32 + lane];
        ushort4 x3 = xb[s3 * 32 + lane];
        ushort4 x4v = xb[s4i * 32 + lane];
        ushort4 x5 = xb[s5 * 32 + lane];
        ushort4 x6 = xb[s6 * 32 + lane];
        ushort4 x7 = xb[s7 * 32 + lane];
        float m1 = (r > 1) ? 1.f : 0.f;
        float m2 = (r > 2) ? 1.f : 0.f;
        float m3 = (r > 3) ? 1.f : 0.f;
        float m4 = (r > 4) ? 1.f : 0.f;
        float m5 = (r > 5) ? 1.f : 0.f;
        float m6 = (r > 6) ? 1.f : 0.f;
        float m7 = (r > 7) ? 1.f : 0.f;
        ax += bf2f(x0.x); ay += bf2f(x0.y); az += bf2f(x0.z); aw += bf2f(x0.w);
        ax += m1 * bf2f(x1.x); ay += m1 * bf2f(x1.y); az += m1 * bf2f(x1.z); aw += m1 * bf2f(x1.w);
        ax += m2 * bf2f(x2.x); ay += m2 * bf2f(x2.y); az += m2 * bf2f(x2.z); aw += m2 * bf2f(x2.w);
        ax += m3 * bf2f(x3.x); ay += m3 * bf2f(x3.y); az += m3 * bf2f(x3.z); aw += m3 * bf2f(x3.w);
        ax += m4 * bf2f(x4v.x); ay += m4 * bf2f(x4v.y); az += m4 * bf2f(x4v.z); aw += m4 * bf2f(x4v.w);
        ax += m5 * bf2f(x5.x); ay += m5 * bf2f(x5.y); az += m5 * bf2f(x5.z); aw += m5 * bf2f(x5.w);
        ax += m6 * bf2f(x6.x); ay += m6 * bf2f(x6.y); az += m6 * bf2f(x6.z); aw += m6 * bf2f(x6.w);
        ax += m7 * bf2f(x7.x); ay += m7 * bf2f(x7.y); az += m7 * bf2f(x7.z); aw += m7 * bf2f(x7.w);
    }
    ushort4 u;
    u.x = f2bf(ax); u.y = f2bf(ay); u.z = f2bf(az); u.w = f2bf(aw);
    hout[node * 32 + lane] = u;
}

// ---------------------------------------------------------------------------
// Persistent-W GEMM + bias + BN-stat accumulation (round-11 verified body).
// Whole bf16 W in registers; grid-stride over 16-row tiles, prefetch depth 1;
// epilogue staged through wave-private LDS for fully-covered 128B-line
// stores. A input is ALWAYS bf16 (int4 loads).
// FUSE_BN=1: BN(statsIn,gmm,bta)+ReLU applied to the bf16 A in the loader.
// OUT_BF16=1: y stored as bf16 (half write traffic; stats stay exact fp32).
// ---------------------------------------------------------------------------
template <int FUSE_BN, int OUT_BF16>
__global__ __launch_bounds__(256, 2) void gin_gemm_k(
    const unsigned short* __restrict__ hin,
    const float* __restrict__ statsIn,
    const float* __restrict__ gmm,
    const float* __restrict__ bta,
    const unsigned short* __restrict__ Wbf, const float* __restrict__ bias,
    float* __restrict__ yf, unsigned short* __restrict__ yh,
    float* __restrict__ statsOut) {
    __shared__ __align__(16) float s_sum[128];
    __shared__ __align__(16) float s_sq[128];
    __shared__ __align__(16) float sc[128];
    __shared__ __align__(16) float sh[128];
    __shared__ __align__(16) float yst[4][16][132];  // fp32 tile (+4 pad)

    const int tid = threadIdx.x;
    const int l = tid & 63, w = tid >> 6;
    const int m = l & 15, q = l >> 4;

    if (tid < 128) {
        s_sum[tid] = 0.f;
        s_sq[tid] = 0.f;
        if (FUSE_BN) {
            const float inv = 1.0f / (float)NN;
            float mean = statsIn[tid] * inv;
            float var = statsIn[128 + tid] * inv - mean * mean;
            float s = gmm[tid] * rsqrtf(var + 1e-5f);
            sc[tid] = s;
            sh[tid] = bta[tid] - mean * s;
        }
    }

    // --- whole W into registers, once per wave ---
    bf16x8 wf[8][4];
#pragma unroll
    for (int ct = 0; ct < 8; ++ct) {
        const unsigned short* wr = Wbf + (size_t)(ct * 16 + m) * 128 + q * 8;
#pragma unroll
        for (int kc = 0; kc < 4; ++kc) {
            BF8 t;
            t.i4 = *(const int4*)(wr + kc * 32);
            wf[ct][kc] = t.v;
        }
    }
    float bc[8];
#pragma unroll
    for (int ct = 0; ct < 8; ++ct) bc[ct] = bias[ct * 16 + m];

    float ps[8], pq[8];
#pragma unroll
    for (int ct = 0; ct < 8; ++ct) { ps[ct] = 0.f; pq[ct] = 0.f; }

    __syncthreads();  // s_sum/s_sq (and sc/sh) visible

    const int NT = NN / 16;              // 6250, exact
    const int stride = gridDim.x * 4;    // waves total
    int t = blockIdx.x * 4 + w;

    const unsigned short* abase = hin + (size_t)m * 128 + q * 8;

    int4 ra[4];
    if (t < NT) {
        const unsigned short* ap = abase + (size_t)t * (16 * 128);
#pragma unroll
        for (int kc = 0; kc < 4; ++kc) ra[kc] = *(const int4*)(ap + kc * 32);
    }

    // bf16 store path aliases this wave's fp32 tile region: 16 x [144] ushort
    unsigned short* ysth = (unsigned short*)&yst[w][0][0];

    while (t < NT) {
        bf16x8 a[4];
#pragma unroll
        for (int kc = 0; kc < 4; ++kc) {
            if (FUSE_BN) {
                BF8 raw;
                raw.i4 = ra[kc];
                const float* scp = sc + kc * 32 + q * 8;
                const float* shp = sh + kc * 32 + q * 8;
                float4 s0 = *(const float4*)scp;
                float4 s1 = *(const float4*)(scp + 4);
                float4 h0 = *(const float4*)shp;
                float4 h1 = *(const float4*)(shp + 4);
                BF8 tt;
                tt.u[0] = f2bf(fmaxf(bf2f(raw.u[0]) * s0.x + h0.x, 0.f));
                tt.u[1] = f2bf(fmaxf(bf2f(raw.u[1]) * s0.y + h0.y, 0.f));
                tt.u[2] = f2bf(fmaxf(bf2f(raw.u[2]) * s0.z + h0.z, 0.f));
                tt.u[3] = f2bf(fmaxf(bf2f(raw.u[3]) * s0.w + h0.w, 0.f));
                tt.u[4] = f2bf(fmaxf(bf2f(raw.u[4]) * s1.x + h1.x, 0.f));
                tt.u[5] = f2bf(fmaxf(bf2f(raw.u[5]) * s1.y + h1.y, 0.f));
                tt.u[6] = f2bf(fmaxf(bf2f(raw.u[6]) * s1.z + h1.z, 0.f));
                tt.u[7] = f2bf(fmaxf(bf2f(raw.u[7]) * s1.w + h1.w, 0.f));
                a[kc] = tt.v;
            } else {
                BF8 tt;
                tt.i4 = ra[kc];
                a[kc] = tt.v;
            }
        }

        int tn = t + stride;
        if (tn < NT) {
            const unsigned short* ap = abase + (size_t)tn * (16 * 128);
#pragma unroll
            for (int kc = 0; kc < 4; ++kc) ra[kc] = *(const int4*)(ap + kc * 32);
        }

        floatx4 acc[8];
#pragma unroll
        for (int ct = 0; ct < 8; ++ct) acc[ct] = (floatx4)0.0f;
#pragma unroll
        for (int kc = 0; kc < 4; ++kc)
#pragma unroll
            for (int ct = 0; ct < 8; ++ct)
                acc[ct] = __builtin_amdgcn_mfma_f32_16x16x32_bf16(a[kc], wf[ct][kc], acc[ct], 0, 0, 0);

        // epilogue: bias + stats (exact fp32), stage tile in wave-private
        // LDS, then store full contiguous rows (fully covered 128B lines)
#pragma unroll
        for (int ct = 0; ct < 8; ++ct) {
#pragma unroll
            for (int i = 0; i < 4; ++i) {
                float yv = acc[ct][i] + bc[ct];
                if (OUT_BF16) {
                    ysth[(q * 4 + i) * 144 + ct * 16 + m] = f2bf(yv);
                } else {
                    yst[w][q * 4 + i][ct * 16 + m] = yv;
                }
                ps[ct] += yv;
                pq[ct] += yv * yv;
            }
        }
        asm volatile("s_waitcnt lgkmcnt(0)" ::: "memory");
        if (OUT_BF16) {
            unsigned short* yb = yh + (size_t)t * (16 * 128);
#pragma unroll
            for (int it = 0; it < 4; ++it) {
                int f = it * 64 + l;
                int row = f >> 4, c8 = f & 15;   // 16 x 16B units per row
                int4 vv = *(const int4*)&ysth[row * 144 + c8 * 8];
                *(int4*)(yb + row * 128 + c8 * 8) = vv;
            }
        } else {
            float* yb = yf + (size_t)t * (16 * 128);
#pragma unroll
            for (int it = 0; it < 8; ++it) {
                int f4 = it * 64 + l;
                int row = f4 >> 5, c4 = f4 & 31;
                float4 vv = *(const float4*)&yst[w][row][c4 * 4];
                *(float4*)(yb + row * 128 + c4 * 4) = vv;
            }
        }
        t = tn;
    }

    // flush register stats: LDS reduce, then 2 global atomics per column
#pragma unroll
    for (int ct = 0; ct < 8; ++ct) {
        atomicAdd(&s_sum[ct * 16 + m], ps[ct]);
        atomicAdd(&s_sq[ct * 16 + m], pq[ct]);
    }
    __syncthreads();
    if (tid < 128) {
        unsafeAtomicAdd(&statsOut[tid], s_sum[tid]);
        unsafeAtomicAdd(&statsOut[128 + tid], s_sq[tid]);
    }
}

// ---------------------------------------------------------------------------
// BN(train, biased var) + ReLU, fp32 in place (final layer only).
// ---------------------------------------------------------------------------
__global__ __launch_bounds__(256) void bn_relu_k(
    const float* __restrict__ y, const float* __restrict__ stats,
    const float* __restrict__ g, const float* __restrict__ beta,
    float* __restrict__ outf) {
    __shared__ __align__(16) float sc[128];
    __shared__ __align__(16) float sh[128];
    int t = threadIdx.x;
    if (t < 128) {
        const float inv = 1.0f / (float)NN;
        float mean = stats[t] * inv;
        float var = stats[128 + t] * inv - mean * mean;
        float s = g[t] * rsqrtf(var + 1e-5f);
        sc[t] = s;
        sh[t] = beta[t] - mean * s;
    }
    __syncthreads();
    const int total4 = NN * 32;
    const float4* y4 = (const float4*)y;
    for (int i = blockIdx.x * 256 + t; i < total4; i += gridDim.x * 256) {
        int c4 = i & 31;
        float4 v = y4[i];
        float4 s = ((const float4*)sc)[c4];
        float4 b = ((const float4*)sh)[c4];
        float r0 = fmaxf(v.x * s.x + b.x, 0.f);
        float r1 = fmaxf(v.y * s.y + b.y, 0.f);
        float r2 = fmaxf(v.z * s.z + b.z, 0.f);
        float r3 = fmaxf(v.w * s.w + b.w, 0.f);
        ((float4*)outf)[i] = make_float4(r0, r1, r2, r3);
    }
}

// ---------------------------------------------------------------------------
extern "C" void kernel_launch(void* const* d_in, const int* in_sizes, int n_in,
                              void* d_out, int out_size, void* d_ws, size_t ws_size,
                              hipStream_t stream) {
    const float* x   = (const float*)d_in[0];
    const int* ei    = (const int*)d_in[1];   // int64 in ref -> int32 from harness
    const float* eps = (const float*)d_in[2];
    const float* W1  = (const float*)d_in[3];
    const float* b1  = (const float*)d_in[4];
    const float* g1  = (const float*)d_in[5];
    const float* be1 = (const float*)d_in[6];
    const float* W2  = (const float*)d_in[7];
    const float* b2  = (const float*)d_in[8];
    const float* g2  = (const float*)d_in[9];
    const float* be2 = (const float*)d_in[10];
    float* out = (float*)d_out;

    // Workspace (~55.1 MB):
    // [deg NPAD][descr 512][offs NPAD][cursor NPAD][ssrc EE+256]
    // [hbuf bf16 25.6MB][y1bf/xbf bf16 25.6MB (ALIASED: xbf dies at
    //  aggregate, y1bf born at gemm1)][stats 512f][wbf 2*128*128 bf16]
    int* deg            = (int*)d_ws;
    unsigned int* descr = (unsigned int*)(deg + NPAD);      // 512 (>= NCHUNK)
    int* offs           = (int*)(descr + 512);
    int* cursor         = offs + NPAD;
    int* ssrc           = cursor + NPAD;
    unsigned short* hbuf = (unsigned short*)(ssrc + EE + 256);
    unsigned short* y1bf = hbuf + (size_t)NN * DD;   // also xbf
    float* stats        = (float*)(y1bf + (size_t)NN * DD);
    unsigned short* wbf = (unsigned short*)(stats + 512);
    ushort4* xbf        = (ushort4*)y1bf;

    // one memset covers deg + lookback descriptors (adjacent)
    hipMemsetAsync(deg, 0, (NPAD + 512) * sizeof(int), stream);

    // hist + x->bf16 convert (12500 extra blocks)
    hist_k<<<2500 + 12500, 256, 0, stream>>>(ei, deg, (const float4*)x, xbf);
    scanlb_k<<<NCHUNK, 256, 0, stream>>>(deg, descr, offs, cursor);
    esort_k<<<2500 + 32, 256, 0, stream>>>(ei, cursor, ssrc, W1, W2, wbf, stats);
    aggregate_k<<<(NN * 32 + 255) / 256, 256, 0, stream>>>(
        xbf, ssrc, offs, deg, eps, (ushort4*)hbuf);

    const int gblocks = 512;  // ~2 blocks/CU, persistent grid-stride
    // gemm1: h(bf16) @ W1^T -> y1 as bf16 (+exact fp32 stats1)
    gin_gemm_k<0, 1><<<gblocks, 256, 0, stream>>>(
        hbuf, nullptr, nullptr, nullptr, wbf, b1, nullptr, y1bf, stats);
    // gemm2: BN1(y1bf)+ReLU in loader, @ W2^T -> y2 fp32 to out (+stats2)
    gin_gemm_k<1, 0><<<gblocks, 256, 0, stream>>>(
        y1bf, stats, g1, be1, wbf + 16384, b2, out, nullptr, stats + 256);
    bn_relu_k<<<4096, 256, 0, stream>>>(out, stats + 256, g2, be2, out);
}